// Round 4
// baseline (313.389 us; speedup 1.0000x reference)
//
#include <hip/hip_runtime.h>
#include <hip/hip_bf16.h>
#include <math.h>

#define T_SEQ 2048
#define NHEAD 16
#define DQK 192      // NOPE + ROPE
#define DNOPE 128
#define DROPE 64
#define LORA_D 512
#define VDIM 128
#define SCALE_F 0.072168783648703216f  // 1/sqrt(192)
#define KC 32
// adaptive split-K: each block handles <= 16 chunks. Per head, tile j
// (q0 = j*64) has n_j = 2j+2 chunks and s_j = ceil(n_j/16) splits:
// j 0..7 -> 1 (direct store), 8..15 -> 2, 16..23 -> 3, 24..31 -> 4.
// blocks/head = 8 + 16 + 24 + 32 = 80; partial slots/head = 72.

typedef short bf16x8 __attribute__((ext_vector_type(8)));   // 8 bf16 = 4 VGPRs
typedef float f32x4 __attribute__((ext_vector_type(4)));

static __device__ __forceinline__ unsigned short f2bf(float x) {
  union { float f; unsigned int u; } v; v.f = x;
  unsigned int r = (v.u + 0x7fff + ((v.u >> 16) & 1)) >> 16;  // RNE
  return (unsigned short)r;
}

// ---------------------------------------------------------------------------
// stage_all: fused input prep. grid (1024, 3).  [R5-proven]
// ---------------------------------------------------------------------------
__global__ __launch_bounds__(256) void stage_all(
    const float* __restrict__ k_c, const float* __restrict__ w_kv_b,
    const float* __restrict__ w_uv, unsigned short* __restrict__ Ab,
    unsigned short* __restrict__ BkT, unsigned short* __restrict__ BvT)
{
  __shared__ float tile[32][33];
  const int bx = blockIdx.x, role = blockIdx.y;
  const int tid = threadIdx.x;
  if (role == 0) {
    int i = (bx * 256 + tid) * 4;
    float4 v = *(const float4*)(k_c + i);
    ushort4 o = {f2bf(v.x), f2bf(v.y), f2bf(v.z), f2bf(v.w)};
    *(ushort4*)(Ab + i) = o;
    return;
  }
  const int tk = tid >> 3, tc4 = (tid & 7) * 4;
  const int wr = tid >> 3, wk4 = (tid & 7) * 4;
  if (role == 1) {
    const int k0 = (bx & 15) * 32, n0 = (bx >> 4) * 32;
    int n = n0 + tc4;
    int col = n + ((n >> 7) << 7);   // skip VDIM half of each head's 256 cols
    float4 v = *(const float4*)&w_kv_b[(size_t)(k0 + tk) * 4096 + col];
    tile[tk][tc4 + 0] = v.x; tile[tk][tc4 + 1] = v.y;
    tile[tk][tc4 + 2] = v.z; tile[tk][tc4 + 3] = v.w;
    __syncthreads();
    ushort4 o = {f2bf(tile[wk4 + 0][wr]), f2bf(tile[wk4 + 1][wr]),
                 f2bf(tile[wk4 + 2][wr]), f2bf(tile[wk4 + 3][wr])};
    *(ushort4*)&BkT[(size_t)(n0 + wr) * LORA_D + k0 + wk4] = o;
  } else {
    const int k0 = (bx & 15) * 32, v0 = ((bx >> 4) & 3) * 32, h = bx >> 6;
    float4 v = *(const float4*)&w_uv[(size_t)h * 65536 + (size_t)(k0 + tk) * 128 + v0 + tc4];
    tile[tk][tc4 + 0] = v.x; tile[tk][tc4 + 1] = v.y;
    tile[tk][tc4 + 2] = v.z; tile[tk][tc4 + 3] = v.w;
    __syncthreads();
    ushort4 o = {f2bf(tile[wk4 + 0][wr]), f2bf(tile[wk4 + 1][wr]),
                 f2bf(tile[wk4 + 2][wr]), f2bf(tile[wk4 + 3][wr])};
    *(ushort4*)&BvT[(size_t)(h * VDIM + v0 + wr) * LORA_D + k0 + wk4] = o;
  }
}

// ---------------------------------------------------------------------------
// prep_gemm: C(2048x2048) = Ab(2048x512) @ BT(2048x512)^T, bf16 in, fp32 acc.
// [R5-proven] 128x128 tile, BK=32, double-buffered LDS + register prefetch.
// ---------------------------------------------------------------------------
__global__ __launch_bounds__(256) void prep_gemm(
    const unsigned short* __restrict__ A, const unsigned short* __restrict__ BkT,
    const unsigned short* __restrict__ BvT, const float* __restrict__ k_pe,
    unsigned short* __restrict__ Kb, unsigned short* __restrict__ Vt)
{
  __shared__ unsigned short As[2][128][40];
  __shared__ unsigned short Bs[2][128][40];
  const int m0 = blockIdx.x * 128;
  const int by = blockIdx.y;
  const int isK = (by < 16);
  const int n0 = (isK ? by : (by - 16)) * 128;
  const unsigned short* BT = isK ? BkT : BvT;
  const int tid = threadIdx.x;
  const int wid = tid >> 6, lane = tid & 63;
  const int l16 = lane & 15, quad = lane >> 4;
  const int wm = (wid >> 1) * 64, wn = (wid & 1) * 64;
  const int srow = tid >> 2, sc = tid & 3;
  uint4 areg[2], breg[2];

  auto load_regs = [&](int k0) {
#pragma unroll
    for (int i = 0; i < 2; ++i) {
      int row = srow + i * 64;
      areg[i] = *(const uint4*)(A + (size_t)(m0 + row) * LORA_D + k0 + sc * 8);
      breg[i] = *(const uint4*)(BT + (size_t)(n0 + row) * LORA_D + k0 + sc * 8);
    }
  };
  auto store_lds = [&](int b) {
#pragma unroll
    for (int i = 0; i < 2; ++i) {
      int row = srow + i * 64;
      *(uint4*)((char*)&As[b][row][0] + sc * 16) = areg[i];
      *(uint4*)((char*)&Bs[b][row][0] + sc * 16) = breg[i];
    }
  };

  f32x4 acc[4][4];
#pragma unroll
  for (int i = 0; i < 4; ++i)
#pragma unroll
    for (int j = 0; j < 4; ++j) acc[i][j] = (f32x4){0.f, 0.f, 0.f, 0.f};

  load_regs(0);
  store_lds(0);
  __syncthreads();
  for (int kc = 0; kc < 16; ++kc) {
    const int cur = kc & 1;
    if (kc < 15) load_regs((kc + 1) * 32);
    bf16x8 af[4], bfr[4];
#pragma unroll
    for (int t = 0; t < 4; ++t) {
      af[t] = *(const bf16x8*)&As[cur][wm + t * 16 + l16][quad * 8];
      bfr[t] = *(const bf16x8*)&Bs[cur][wn + t * 16 + l16][quad * 8];
    }
#pragma unroll
    for (int mt = 0; mt < 4; ++mt)
#pragma unroll
      for (int nt = 0; nt < 4; ++nt)
        acc[mt][nt] = __builtin_amdgcn_mfma_f32_16x16x32_bf16(af[mt], bfr[nt], acc[mt][nt], 0, 0, 0);
    if (kc < 15) store_lds(cur ^ 1);
    __syncthreads();
  }

  if (isK) {
    const int h = by;
#pragma unroll
    for (int mt = 0; mt < 4; ++mt)
#pragma unroll
      for (int nt = 0; nt < 4; ++nt) {
        int m = m0 + wm + mt * 16 + quad * 4;
        int d = wn + nt * 16 + l16;
#pragma unroll
        for (int r = 0; r < 4; ++r)
          Kb[(size_t)h * (T_SEQ * DQK) + (size_t)(m + r) * DQK + d] =
              f2bf(acc[mt][nt][r]);
      }
    // fused rope: Kb[h][m0+row][128+c] = bf16(k_pe[m0+row][c])
    for (int e = tid; e < 128 * 16; e += 256) {
      int row = e >> 4, c4 = (e & 15) * 4;
      float4 v = *(const float4*)&k_pe[(size_t)(m0 + row) * DROPE + c4];
      ushort4 o = {f2bf(v.x), f2bf(v.y), f2bf(v.z), f2bf(v.w)};
      *(ushort4*)&Kb[(size_t)h * (T_SEQ * DQK) + (size_t)(m0 + row) * DQK + DNOPE + c4] = o;
    }
  } else {
#pragma unroll
    for (int mt = 0; mt < 4; ++mt)
#pragma unroll
      for (int nt = 0; nt < 4; ++nt) {
        int n = n0 + wn + nt * 16 + l16;
        int m = m0 + wm + mt * 16 + quad * 4;
        ushort4 o = {f2bf(acc[mt][nt][0]), f2bf(acc[mt][nt][1]),
                     f2bf(acc[mt][nt][2]), f2bf(acc[mt][nt][3])};
        *(ushort4*)&Vt[(size_t)n * T_SEQ + m] = o;
      }
  }
}

// ---------------------------------------------------------------------------
// flash_mfma R4: BARRIER-FREE. R3 evidence: 5-block/CU LDS-staging thrashed
// L2 (FETCH 53->267 MB); R2 evidence: barrier-pipelined chunks cost ~4-5k
// cycles each vs ~1k of work. Fix: K/V MFMA fragments load DIRECTLY from
// global (L2-resident: 2 heads/XCD ~ 2.6 MB) into registers. K is register-
// double-buffered one chunk ahead (kA/kB); V issues at chunk top, consumed
// after QK+exp (~400cy, hides L2 latency). LDS = wave-private Ps only (5 KB).
// Zero __syncthreads in the whole kernel. S/P/O layouts identical to R2.
// launch_bounds(256,2): ~225 VGPR, 2 waves/SIMD, 512 co-resident blocks
// (= R2's co-residency -> R2's FETCH locality). Adaptive split-K schedule,
// dense partial slots, heavy-first dispatch, XCD head clustering kept.
// ---------------------------------------------------------------------------
__global__ __launch_bounds__(256, 2) void flash_mfma(
    const float* __restrict__ Q, const unsigned short* __restrict__ K,
    const unsigned short* __restrict__ Vt, float* __restrict__ outp,
    float* __restrict__ Opart, float* __restrict__ Lpart, int adaptive)
{
  __shared__ unsigned short Ps[4][16][40];   // wave-private P transpose tiles
  const int id = blockIdx.x;
  const int h = ((id & 7) << 1) | ((id >> 3) & 1);   // cluster heads per XCD
  int q0, c0, c1, slot, direct;
  if (adaptive) {
    const int b = 79 - (id >> 4);                    // heavy splits first
    int j, sp, s;
    if (b < 8)       { j = b;               sp = 0;            s = 1; }
    else if (b < 24) { j = 8 + (b - 8) / 2; sp = (b - 8) % 2;  s = 2; }
    else if (b < 48) { j = 16 + (b - 24) / 3; sp = (b - 24) % 3; s = 3; }
    else             { j = 24 + (b - 48) / 4; sp = (b - 48) % 4; s = 4; }
    q0 = j * 64;
    const int n = 2 * j + 2;
    c0 = (n * sp) / s;
    c1 = (n * (sp + 1)) / s;
    direct = (s == 1);
    slot = h * 72 + (b - 8);                         // valid iff !direct
  } else {
    q0 = (31 - (id >> 4)) * 64;
    c0 = 0; c1 = q0 / KC + 2; direct = 1; slot = 0;
  }
  const int tid = threadIdx.x;
  const int wid = tid >> 6;
  const int lane = tid & 63;
  const int l16 = lane & 15;
  const int quad = lane >> 4;
  const int myrow = q0 + wid * 16 + quad * 4;
  const int nch = c1 - c0;                           // >= 1 always

  const unsigned short* Kh = K + (size_t)h * T_SEQ * DQK;
  const unsigned short* Vth = Vt + (size_t)h * VDIM * T_SEQ;

  // ---- Q fragments direct from global (fp32 -> bf16 in regs, one-time) ----
  bf16x8 qf[6];
  {
    const float* Qrow = Q + (size_t)(q0 + wid * 16 + l16) * (NHEAD * DQK) + h * DQK;
#pragma unroll
    for (int ks = 0; ks < 6; ++ks) {
      float4 a = *(const float4*)(Qrow + ks * 32 + quad * 8);
      float4 b = *(const float4*)(Qrow + ks * 32 + quad * 8 + 4);
      bf16x8 q;
      q[0] = (short)f2bf(a.x); q[1] = (short)f2bf(a.y);
      q[2] = (short)f2bf(a.z); q[3] = (short)f2bf(a.w);
      q[4] = (short)f2bf(b.x); q[5] = (short)f2bf(b.y);
      q[6] = (short)f2bf(b.z); q[7] = (short)f2bf(b.w);
      qf[ks] = q;
    }
  }

  bf16x8 kA[12], kB[12], vf[8];
  // K fragment: rows (s0+l16, s0+16+l16), 16B at col ks*32+quad*8.
  // Wave footprint per load: 16 rows x 64B fully-used lines (L2-served).
  auto load_K = [&](bf16x8 (&kf)[12], int s0) {
#pragma unroll
    for (int ks = 0; ks < 6; ++ks) {
      kf[2 * ks]     = *(const bf16x8*)(Kh + (size_t)(s0 + l16) * DQK + ks * 32 + quad * 8);
      kf[2 * ks + 1] = *(const bf16x8*)(Kh + (size_t)(s0 + 16 + l16) * DQK + ks * 32 + quad * 8);
    }
  };
  auto load_V = [&](int s0) {
#pragma unroll
    for (int nt = 0; nt < 8; ++nt)
      vf[nt] = *(const bf16x8*)(Vth + (size_t)(nt * 16 + l16) * T_SEQ + s0 + quad * 8);
  };

  f32x4 oacc[8];
#pragma unroll
  for (int i = 0; i < 8; ++i) oacc[i] = (f32x4){0.f, 0.f, 0.f, 0.f};
  float lsum[4] = {0.f, 0.f, 0.f, 0.f};

  load_K(kA, c0 * KC);                               // chunk 0 K in flight

  auto step = [&](bf16x8 (&kf)[12], bf16x8 (&nk)[12], int ck) {
    const int s0 = (c0 + ck) * KC;
    load_V(s0);                        // consumed after QK+exp (~400cy)
    if (ck + 1 < nch) load_K(nk, s0 + KC);           // next chunk K

    // ---- S = Q @ K^T (waits only on kf; vf + nk stay outstanding) ----
    f32x4 sacc0 = (f32x4){0.f, 0.f, 0.f, 0.f};
    f32x4 sacc1 = (f32x4){0.f, 0.f, 0.f, 0.f};
    __builtin_amdgcn_s_setprio(1);
#pragma unroll
    for (int ks = 0; ks < 6; ++ks) {
      sacc0 = __builtin_amdgcn_mfma_f32_16x16x32_bf16(qf[ks], kf[2 * ks],     sacc0, 0, 0, 0);
      sacc1 = __builtin_amdgcn_mfma_f32_16x16x32_bf16(qf[ks], kf[2 * ks + 1], sacc1, 0, 0, 0);
    }
    __builtin_amdgcn_s_setprio(0);

    // ---- p = exp(s) (no max-subtraction; scores bounded), mask via p=0 ----
#pragma unroll
    for (int r = 0; r < 4; ++r) {
      int row = myrow + r;
      float p0 = (s0 + l16 <= row) ? __expf(sacc0[r] * SCALE_F) : 0.f;
      float p1 = (s0 + 16 + l16 <= row) ? __expf(sacc1[r] * SCALE_F) : 0.f;
      lsum[r] += p0 + p1;
      Ps[wid][quad * 4 + r][l16] = f2bf(p0);
      Ps[wid][quad * 4 + r][16 + l16] = f2bf(p1);
    }

    // ---- PV (Ps wave-private; same-wave DS ordering suffices) ----
    bf16x8 pf = *(const bf16x8*)&Ps[wid][l16][quad * 8];
    __builtin_amdgcn_s_setprio(1);
#pragma unroll
    for (int nt = 0; nt < 8; ++nt)
      oacc[nt] = __builtin_amdgcn_mfma_f32_16x16x32_bf16(pf, vf[nt], oacc[nt], 0, 0, 0);
    __builtin_amdgcn_s_setprio(0);
  };

  int ck = 0;
  for (; ck + 2 <= nch; ck += 2) {
    step(kA, kB, ck);
    step(kB, kA, ck + 1);
  }
  if (ck < nch) step(kA, kB, ck);

  // ---- reduce l across the 16 lanes of each quad-row group ----
#pragma unroll
  for (int off = 1; off < 16; off <<= 1)
#pragma unroll
    for (int r = 0; r < 4; ++r) lsum[r] += __shfl_xor(lsum[r], off);

  if (direct) {
    float inv[4];
#pragma unroll
    for (int r = 0; r < 4; ++r) inv[r] = 1.f / lsum[r];
#pragma unroll
    for (int nt = 0; nt < 8; ++nt)
#pragma unroll
      for (int r = 0; r < 4; ++r)
        outp[(size_t)(myrow + r) * (NHEAD * VDIM) + h * VDIM + nt * 16 + l16] =
            oacc[nt][r] * inv[r];
  } else {
    // dense block-local partial slot: [64][128] fp32, fully-written lines
    const int rbase = wid * 16 + quad * 4;
#pragma unroll
    for (int nt = 0; nt < 8; ++nt)
#pragma unroll
      for (int r = 0; r < 4; ++r)
        Opart[(size_t)slot * 8192 + (rbase + r) * 128 + nt * 16 + l16] =
            oacc[nt][r];
    if (l16 == 0)
#pragma unroll
      for (int r = 0; r < 4; ++r)
        Lpart[slot * 64 + rbase + r] = lsum[r];
  }
}

// ---------------------------------------------------------------------------
// reduce_out: combine partial slots for split tiles (j >= 8 only).
// grid 384 = 16 heads x 24 tiles; sums s in {2,3,4} dense 32 KB slots.
// ---------------------------------------------------------------------------
__global__ __launch_bounds__(256) void reduce_out(
    const float* __restrict__ Opart, const float* __restrict__ Lpart,
    float* __restrict__ outp)
{
  const int t = blockIdx.x;
  const int h = t & 15;
  const int j = 8 + (t >> 4);
  int s, b0;
  if (j < 16)      { s = 2; b0 = 8 + (j - 8) * 2; }
  else if (j < 24) { s = 3; b0 = 24 + (j - 16) * 3; }
  else             { s = 4; b0 = 48 + (j - 24) * 4; }
  const int slot = h * 72 + (b0 - 8);
  const int q0 = j * 64;
  const int tid = threadIdx.x;
#pragma unroll
  for (int i = 0; i < 8; ++i) {
    const int f4 = tid + i * 256;            // [0,2048) float4 within tile
    const int row = f4 >> 5, cc = f4 & 31;
    float ax = 0.f, ay = 0.f, az = 0.f, aw = 0.f, l = 0.f;
    for (int k = 0; k < s; ++k) {
      float4 v = ((const float4*)Opart)[(size_t)(slot + k) * 2048 + f4];
      ax += v.x; ay += v.y; az += v.z; aw += v.w;
      l += Lpart[(slot + k) * 64 + row];
    }
    const float inv = 1.f / l;
    float4 o = {ax * inv, ay * inv, az * inv, aw * inv};
    ((float4*)outp)[(size_t)(q0 + row) * 512 + h * 32 + cc] = o;
  }
}

// ---------------------------------------------------------------------------
extern "C" void kernel_launch(void* const* d_in, const int* in_sizes, int n_in,
                              void* d_out, int out_size, void* d_ws, size_t ws_size,
                              hipStream_t stream) {
  const float* query  = (const float*)d_in[0];  // (T, H, 192)
  const float* k_c    = (const float*)d_in[1];  // (T, 512)
  const float* k_pe   = (const float*)d_in[2];  // (T, 64)
  const float* w_kv_b = (const float*)d_in[3];  // (512, 4096)
  const float* w_uv   = (const float*)d_in[4];  // (16, 512, 128)
  float* outp = (float*)d_out;                  // (T, 2048)

  unsigned short* Kb  = (unsigned short*)d_ws;             // (H,T,192) bf16
  unsigned short* Vt  = Kb + (size_t)NHEAD * T_SEQ * DQK;  // (H,128,T) bf16
  unsigned short* Ab  = Vt + (size_t)NHEAD * VDIM * T_SEQ; // (T,512)
  unsigned short* BkT = Ab + (size_t)T_SEQ * LORA_D;       // (2048,512)
  unsigned short* BvT = BkT + (size_t)2048 * LORA_D;       // (2048,512)
  float* Opart = (float*)(BvT + (size_t)2048 * LORA_D);    // 1152 x [64][128] fp32
  float* Lpart = Opart + (size_t)16 * 72 * 64 * 128;       // 1152 x [64] fp32
  const size_t need =
      (size_t)((char*)(Lpart + (size_t)16 * 72 * 64) - (char*)d_ws);
  const int adaptive = (ws_size >= need) ? 1 : 0;   // safe fallback

  stage_all<<<dim3(1024, 3), 256, 0, stream>>>(k_c, w_kv_b, w_uv, Ab, BkT, BvT);
  prep_gemm<<<dim3(16, 32), 256, 0, stream>>>(Ab, BkT, BvT, k_pe, Kb, Vt);
  flash_mfma<<<adaptive ? 1280 : 512, 256, 0, stream>>>(query, Kb, Vt, outp,
                                                        Opart, Lpart, adaptive);
  if (adaptive)
    reduce_out<<<384, 256, 0, stream>>>(Opart, Lpart, outp);
}

// Round 5
// 263.825 us; speedup vs baseline: 1.1879x; 1.1879x over previous
//
#include <hip/hip_runtime.h>
#include <hip/hip_bf16.h>
#include <math.h>

#define T_SEQ 2048
#define NHEAD 16
#define DQK 192      // NOPE + ROPE
#define DNOPE 128
#define DROPE 64
#define LORA_D 512
#define VDIM 128
#define SCALE_F 0.072168783648703216f  // 1/sqrt(192)
#define KC 32
// adaptive split-K: each block handles <= 16 chunks. Per head, tile j
// (q0 = j*64) has n_j = 2j+2 chunks and s_j = ceil(n_j/16) splits:
// j 0..7 -> 1 (direct store), 8..15 -> 2, 16..23 -> 3, 24..31 -> 4.
// blocks/head = 8 + 16 + 24 + 32 = 80; partial slots/head = 72.

typedef short bf16x8 __attribute__((ext_vector_type(8)));   // 8 bf16 = 4 VGPRs
typedef float f32x4 __attribute__((ext_vector_type(4)));

static __device__ __forceinline__ unsigned short f2bf(float x) {
  union { float f; unsigned int u; } v; v.f = x;
  unsigned int r = (v.u + 0x7fff + ((v.u >> 16) & 1)) >> 16;  // RNE
  return (unsigned short)r;
}

// ---------------------------------------------------------------------------
// stage_all: fused input prep. grid (1024, 3).  [R5-proven]
//  y==0: cast k_c fp32 (T,512) -> bf16 Ab
//  y==1: BkT[n][k] = bf16(w_kv_b[k][(n>>7)*256 + (n&127)])   (32x32 transpose)
//  y==2: BvT[(h*128+v)][k] = bf16(w_uv[h][k][v])             (32x32 transpose)
// ---------------------------------------------------------------------------
__global__ __launch_bounds__(256) void stage_all(
    const float* __restrict__ k_c, const float* __restrict__ w_kv_b,
    const float* __restrict__ w_uv, unsigned short* __restrict__ Ab,
    unsigned short* __restrict__ BkT, unsigned short* __restrict__ BvT)
{
  __shared__ float tile[32][33];
  const int bx = blockIdx.x, role = blockIdx.y;
  const int tid = threadIdx.x;
  if (role == 0) {
    int i = (bx * 256 + tid) * 4;
    float4 v = *(const float4*)(k_c + i);
    ushort4 o = {f2bf(v.x), f2bf(v.y), f2bf(v.z), f2bf(v.w)};
    *(ushort4*)(Ab + i) = o;
    return;
  }
  const int tk = tid >> 3, tc4 = (tid & 7) * 4;
  const int wr = tid >> 3, wk4 = (tid & 7) * 4;
  if (role == 1) {
    const int k0 = (bx & 15) * 32, n0 = (bx >> 4) * 32;
    int n = n0 + tc4;
    int col = n + ((n >> 7) << 7);   // skip VDIM half of each head's 256 cols
    float4 v = *(const float4*)&w_kv_b[(size_t)(k0 + tk) * 4096 + col];
    tile[tk][tc4 + 0] = v.x; tile[tk][tc4 + 1] = v.y;
    tile[tk][tc4 + 2] = v.z; tile[tk][tc4 + 3] = v.w;
    __syncthreads();
    ushort4 o = {f2bf(tile[wk4 + 0][wr]), f2bf(tile[wk4 + 1][wr]),
                 f2bf(tile[wk4 + 2][wr]), f2bf(tile[wk4 + 3][wr])};
    *(ushort4*)&BkT[(size_t)(n0 + wr) * LORA_D + k0 + wk4] = o;
  } else {
    const int k0 = (bx & 15) * 32, v0 = ((bx >> 4) & 3) * 32, h = bx >> 6;
    float4 v = *(const float4*)&w_uv[(size_t)h * 65536 + (size_t)(k0 + tk) * 128 + v0 + tc4];
    tile[tk][tc4 + 0] = v.x; tile[tk][tc4 + 1] = v.y;
    tile[tk][tc4 + 2] = v.z; tile[tk][tc4 + 3] = v.w;
    __syncthreads();
    ushort4 o = {f2bf(tile[wk4 + 0][wr]), f2bf(tile[wk4 + 1][wr]),
                 f2bf(tile[wk4 + 2][wr]), f2bf(tile[wk4 + 3][wr])};
    *(ushort4*)&BvT[(size_t)(h * VDIM + v0 + wr) * LORA_D + k0 + wk4] = o;
  }
}

// ---------------------------------------------------------------------------
// prep_gemm R5: main loop unchanged (128x128 tile, BK=32, LDS dbuf, register
// prefetch). NEW: both epilogues route the output tile through LDS (reusing
// the As/Bs region, dead after the last barrier) so Kb and Vt are written as
// fully-coalesced 16B/lane stores (128B runs per row) instead of scalar 2B
// stores at 384B stride (K) / half-line 4KB-strided stores (V).
// ---------------------------------------------------------------------------
__global__ __launch_bounds__(256) void prep_gemm(
    const unsigned short* __restrict__ A, const unsigned short* __restrict__ BkT,
    const unsigned short* __restrict__ BvT, const float* __restrict__ k_pe,
    unsigned short* __restrict__ Kb, unsigned short* __restrict__ Vt)
{
  // flat LDS carve (40960 B):
  //   As[b][row][40] = SMEM[b*5120 + row*40 + c]
  //   Bs[b][row][40] = SMEM[10240 + b*5120 + row*40 + c]
  //   epilogue reuse: E[128][136] bf16 (17408 shorts)
  __shared__ unsigned short SMEM[20480];
  const int m0 = blockIdx.x * 128;
  const int by = blockIdx.y;
  const int isK = (by < 16);
  const int n0 = (isK ? by : (by - 16)) * 128;
  const unsigned short* BT = isK ? BkT : BvT;
  const int tid = threadIdx.x;
  const int wid = tid >> 6, lane = tid & 63;
  const int l16 = lane & 15, quad = lane >> 4;
  const int wm = (wid >> 1) * 64, wn = (wid & 1) * 64;
  const int srow = tid >> 2, sc = tid & 3;
  uint4 areg[2], breg[2];

  auto load_regs = [&](int k0) {
#pragma unroll
    for (int i = 0; i < 2; ++i) {
      int row = srow + i * 64;
      areg[i] = *(const uint4*)(A + (size_t)(m0 + row) * LORA_D + k0 + sc * 8);
      breg[i] = *(const uint4*)(BT + (size_t)(n0 + row) * LORA_D + k0 + sc * 8);
    }
  };
  auto store_lds = [&](int b) {
#pragma unroll
    for (int i = 0; i < 2; ++i) {
      int row = srow + i * 64;
      *(uint4*)((char*)&SMEM[b * 5120 + row * 40] + sc * 16) = areg[i];
      *(uint4*)((char*)&SMEM[10240 + b * 5120 + row * 40] + sc * 16) = breg[i];
    }
  };

  f32x4 acc[4][4];
#pragma unroll
  for (int i = 0; i < 4; ++i)
#pragma unroll
    for (int j = 0; j < 4; ++j) acc[i][j] = (f32x4){0.f, 0.f, 0.f, 0.f};

  load_regs(0);
  store_lds(0);
  __syncthreads();
  for (int kc = 0; kc < 16; ++kc) {
    const int cur = kc & 1;
    if (kc < 15) load_regs((kc + 1) * 32);
    bf16x8 af[4], bfr[4];
#pragma unroll
    for (int t = 0; t < 4; ++t) {
      af[t] = *(const bf16x8*)&SMEM[cur * 5120 + (wm + t * 16 + l16) * 40 + quad * 8];
      bfr[t] = *(const bf16x8*)&SMEM[10240 + cur * 5120 + (wn + t * 16 + l16) * 40 + quad * 8];
    }
#pragma unroll
    for (int mt = 0; mt < 4; ++mt)
#pragma unroll
      for (int nt = 0; nt < 4; ++nt)
        acc[mt][nt] = __builtin_amdgcn_mfma_f32_16x16x32_bf16(af[mt], bfr[nt], acc[mt][nt], 0, 0, 0);
    if (kc < 15) store_lds(cur ^ 1);
    __syncthreads();
  }

  // ---- epilogue: stage bf16 tile in LDS (As/Bs dead), store coalesced ----
  unsigned short* E = SMEM;   // [128][136]
  if (isK) {
    // E[m_local][d]
#pragma unroll
    for (int mt = 0; mt < 4; ++mt)
#pragma unroll
      for (int nt = 0; nt < 4; ++nt) {
        int ml = wm + mt * 16 + quad * 4;
        int d = wn + nt * 16 + l16;
#pragma unroll
        for (int r = 0; r < 4; ++r)
          E[(ml + r) * 136 + d] = f2bf(acc[mt][nt][r]);
      }
  } else {
    // E[n_local][m_local]
#pragma unroll
    for (int mt = 0; mt < 4; ++mt)
#pragma unroll
      for (int nt = 0; nt < 4; ++nt) {
        int ml = wm + mt * 16 + quad * 4;
        int nl = wn + nt * 16 + l16;
#pragma unroll
        for (int r = 0; r < 4; ++r)
          E[nl * 136 + ml + r] = f2bf(acc[mt][nt][r]);
      }
  }
  __syncthreads();

  if (isK) {
    const int h = by;
    // 128 rows x 128 cols, 16B/lane, 8 lanes per row -> 128B runs
#pragma unroll
    for (int i = 0; i < 8; ++i) {
      int idx = (i * 256 + tid) * 8;
      int row = idx >> 7, col = idx & 127;
      uint4 v = *(const uint4*)&E[row * 136 + col];
      *(uint4*)&Kb[(size_t)h * (T_SEQ * DQK) + (size_t)(m0 + row) * DQK + col] = v;
    }
    // fused rope: Kb[h][m0+row][128+c] = bf16(k_pe[m0+row][c])
    for (int e = tid; e < 128 * 16; e += 256) {
      int row = e >> 4, c4 = (e & 15) * 4;
      float4 v = *(const float4*)&k_pe[(size_t)(m0 + row) * DROPE + c4];
      ushort4 o = {f2bf(v.x), f2bf(v.y), f2bf(v.z), f2bf(v.w)};
      *(ushort4*)&Kb[(size_t)h * (T_SEQ * DQK) + (size_t)(m0 + row) * DQK + DNOPE + c4] = o;
    }
  } else {
#pragma unroll
    for (int i = 0; i < 8; ++i) {
      int idx = (i * 256 + tid) * 8;
      int row = idx >> 7, col = idx & 127;   // row = n_local, col = m_local
      uint4 v = *(const uint4*)&E[row * 136 + col];
      *(uint4*)&Vt[(size_t)(n0 + row) * T_SEQ + m0 + col] = v;
    }
  }
}

// ---------------------------------------------------------------------------
// flash_mfma: EXACT R2 version (best measured: ~135 us). Work-proportional
// split-K (<=16 chunks/block), LDS K/V double-buffer + register prefetch,
// 1 barrier/chunk, no-max softmax, dense block-local partial slots, direct
// store for single-split tiles, setprio around MFMA clusters, heavy-first
// dispatch, XCD head clustering. R3 (5 blocks/CU, single buffer) thrashed L2;
// R4 (barrier-free reg fragments) was defeated by compiler load sinking.
// ---------------------------------------------------------------------------
__global__ __launch_bounds__(256, 3) void flash_mfma(
    const float* __restrict__ Q, const unsigned short* __restrict__ K,
    const unsigned short* __restrict__ Vt, float* __restrict__ outp,
    float* __restrict__ Opart, float* __restrict__ Lpart, int adaptive)
{
  __shared__ unsigned short SM[2 * KC * 200];   // union: Qs[64][200] / Ks[2][32][200]
  __shared__ unsigned short Vs[2][128][40];
  __shared__ unsigned short Ps[4][16][40];
  const int id = blockIdx.x;
  const int h = ((id & 7) << 1) | ((id >> 3) & 1);   // cluster heads per XCD
  int q0, c0, c1, slot, direct;
  if (adaptive) {
    const int b = 79 - (id >> 4);                    // heavy splits first
    int j, sp, s;
    if (b < 8)       { j = b;               sp = 0;            s = 1; }
    else if (b < 24) { j = 8 + (b - 8) / 2; sp = (b - 8) % 2;  s = 2; }
    else if (b < 48) { j = 16 + (b - 24) / 3; sp = (b - 24) % 3; s = 3; }
    else             { j = 24 + (b - 48) / 4; sp = (b - 48) % 4; s = 4; }
    q0 = j * 64;
    const int n = 2 * j + 2;
    c0 = (n * sp) / s;
    c1 = (n * (sp + 1)) / s;
    direct = (s == 1);
    slot = h * 72 + (b - 8);                         // valid iff !direct
  } else {
    q0 = (31 - (id >> 4)) * 64;
    c0 = 0; c1 = q0 / KC + 2; direct = 1; slot = 0;
  }
  const int tid = threadIdx.x;
  const int wid = tid >> 6;
  const int lane = tid & 63;
  const int l16 = lane & 15;
  const int quad = lane >> 4;
  const int myrow = q0 + wid * 16 + quad * 4;
  const int nch = c1 - c0;                           // >= 1 always

  const unsigned short* Kh = K + (size_t)h * T_SEQ * DQK;
  const unsigned short* Vth = Vt + (size_t)h * VDIM * T_SEQ;

  uint4 kreg[3], vreg[2];
  auto load_regs = [&](int s0) {
#pragma unroll
    for (int i = 0; i < 3; ++i) {
      int s = tid + i * 256, row = s / 24, c = s - row * 24;
      kreg[i] = *(const uint4*)(Kh + (size_t)(s0 + row) * DQK + c * 8);
    }
#pragma unroll
    for (int i = 0; i < 2; ++i) {
      int s = tid + i * 256, row = s >> 2, c = s & 3;
      vreg[i] = *(const uint4*)(Vth + (size_t)row * T_SEQ + s0 + c * 8);
    }
  };
  auto store_lds = [&](int b) {
#pragma unroll
    for (int i = 0; i < 3; ++i) {
      int s = tid + i * 256, row = s / 24, c = s - row * 24;
      *(uint4*)((char*)&SM[b * (KC * 200) + row * 200] + c * 16) = kreg[i];
    }
#pragma unroll
    for (int i = 0; i < 2; ++i) {
      int s = tid + i * 256, row = s >> 2, c = s & 3;
      *(uint4*)((char*)&Vs[b][row][0] + c * 16) = vreg[i];
    }
  };

  // ---- prefetch first chunk of this split while staging Q through SM ----
  load_regs(c0 * KC);
  for (int e = tid; e < 64 * 48; e += 256) {
    int row = e / 48, col = (e % 48) * 4;
    float4 q4 = *(const float4*)&Q[(size_t)(q0 + row) * (NHEAD * DQK) + h * DQK + col];
    ushort4 qp = {f2bf(q4.x), f2bf(q4.y), f2bf(q4.z), f2bf(q4.w)};
    *(ushort4*)&SM[row * 200 + col] = qp;
  }
  __syncthreads();
  bf16x8 qf[6];
#pragma unroll
  for (int ks = 0; ks < 6; ++ks)
    qf[ks] = *(const bf16x8*)&SM[(wid * 16 + l16) * 200 + ks * 32 + quad * 8];
  __syncthreads();           // Q reads done before region becomes Ks
  store_lds(0);
  __syncthreads();           // buffers 0 visible

  f32x4 oacc[8];
#pragma unroll
  for (int i = 0; i < 8; ++i) oacc[i] = (f32x4){0.f, 0.f, 0.f, 0.f};
  float lsum[4] = {0.f, 0.f, 0.f, 0.f};

  for (int ck = 0; ck < nch; ++ck) {
    const int cur = ck & 1;
    const int s0 = (c0 + ck) * KC;
    if (ck + 1 < nch) load_regs(s0 + KC);

    // ---- S = Q @ K^T ----
    f32x4 sacc[2];
    sacc[0] = (f32x4){0.f, 0.f, 0.f, 0.f};
    sacc[1] = (f32x4){0.f, 0.f, 0.f, 0.f};
    __builtin_amdgcn_s_setprio(1);
#pragma unroll
    for (int ks = 0; ks < 6; ++ks) {
      bf16x8 kf0 = *(const bf16x8*)&SM[cur * (KC * 200) + l16 * 200 + ks * 32 + quad * 8];
      bf16x8 kf1 = *(const bf16x8*)&SM[cur * (KC * 200) + (16 + l16) * 200 + ks * 32 + quad * 8];
      sacc[0] = __builtin_amdgcn_mfma_f32_16x16x32_bf16(qf[ks], kf0, sacc[0], 0, 0, 0);
      sacc[1] = __builtin_amdgcn_mfma_f32_16x16x32_bf16(qf[ks], kf1, sacc[1], 0, 0, 0);
    }
    __builtin_amdgcn_s_setprio(0);

    // ---- p = exp(s) (no max-subtraction; scores bounded), mask via p=0 ----
#pragma unroll
    for (int r = 0; r < 4; ++r) {
      int row = myrow + r;
      float p0 = (s0 + l16 <= row) ? __expf(sacc[0][r] * SCALE_F) : 0.f;
      float p1 = (s0 + 16 + l16 <= row) ? __expf(sacc[1][r] * SCALE_F) : 0.f;
      lsum[r] += p0 + p1;
      Ps[wid][quad * 4 + r][l16] = f2bf(p0);
      Ps[wid][quad * 4 + r][16 + l16] = f2bf(p1);
    }

    // ---- PV (P wave-private; same-wave DS ordering suffices) ----
    bf16x8 pf = *(const bf16x8*)&Ps[wid][l16][quad * 8];
    __builtin_amdgcn_s_setprio(1);
#pragma unroll
    for (int nt = 0; nt < 8; ++nt) {
      bf16x8 vf = *(const bf16x8*)&Vs[cur][nt * 16 + l16][quad * 8];
      oacc[nt] = __builtin_amdgcn_mfma_f32_16x16x32_bf16(pf, vf, oacc[nt], 0, 0, 0);
    }
    __builtin_amdgcn_s_setprio(0);

    if (ck + 1 < nch) store_lds(cur ^ 1);
    __syncthreads();
  }

  // ---- reduce l across the 16 lanes of each quad-row group ----
#pragma unroll
  for (int off = 1; off < 16; off <<= 1)
#pragma unroll
    for (int r = 0; r < 4; ++r) lsum[r] += __shfl_xor(lsum[r], off);

  if (direct) {
    float inv[4];
#pragma unroll
    for (int r = 0; r < 4; ++r) inv[r] = 1.f / lsum[r];
#pragma unroll
    for (int nt = 0; nt < 8; ++nt)
#pragma unroll
      for (int r = 0; r < 4; ++r)
        outp[(size_t)(myrow + r) * (NHEAD * VDIM) + h * VDIM + nt * 16 + l16] =
            oacc[nt][r] * inv[r];
  } else {
    // dense block-local partial slot: [64][128] fp32, fully-written lines
    const int rbase = wid * 16 + quad * 4;
#pragma unroll
    for (int nt = 0; nt < 8; ++nt)
#pragma unroll
      for (int r = 0; r < 4; ++r)
        Opart[(size_t)slot * 8192 + (rbase + r) * 128 + nt * 16 + l16] =
            oacc[nt][r];
    if (l16 == 0)
#pragma unroll
      for (int r = 0; r < 4; ++r)
        Lpart[slot * 64 + rbase + r] = lsum[r];
  }
}

// ---------------------------------------------------------------------------
// reduce_out: combine partial slots for split tiles (j >= 8 only).
// grid 384 = 16 heads x 24 tiles; sums s in {2,3,4} dense 32 KB slots.
// ---------------------------------------------------------------------------
__global__ __launch_bounds__(256) void reduce_out(
    const float* __restrict__ Opart, const float* __restrict__ Lpart,
    float* __restrict__ outp)
{
  const int t = blockIdx.x;
  const int h = t & 15;
  const int j = 8 + (t >> 4);
  int s, b0;
  if (j < 16)      { s = 2; b0 = 8 + (j - 8) * 2; }
  else if (j < 24) { s = 3; b0 = 24 + (j - 16) * 3; }
  else             { s = 4; b0 = 48 + (j - 24) * 4; }
  const int slot = h * 72 + (b0 - 8);
  const int q0 = j * 64;
  const int tid = threadIdx.x;
#pragma unroll
  for (int i = 0; i < 8; ++i) {
    const int f4 = tid + i * 256;            // [0,2048) float4 within tile
    const int row = f4 >> 5, cc = f4 & 31;
    float ax = 0.f, ay = 0.f, az = 0.f, aw = 0.f, l = 0.f;
    for (int k = 0; k < s; ++k) {
      float4 v = ((const float4*)Opart)[(size_t)(slot + k) * 2048 + f4];
      ax += v.x; ay += v.y; az += v.z; aw += v.w;
      l += Lpart[(slot + k) * 64 + row];
    }
    const float inv = 1.f / l;
    float4 o = {ax * inv, ay * inv, az * inv, aw * inv};
    ((float4*)outp)[(size_t)(q0 + row) * 512 + h * 32 + cc] = o;
  }
}

// ---------------------------------------------------------------------------
extern "C" void kernel_launch(void* const* d_in, const int* in_sizes, int n_in,
                              void* d_out, int out_size, void* d_ws, size_t ws_size,
                              hipStream_t stream) {
  const float* query  = (const float*)d_in[0];  // (T, H, 192)
  const float* k_c    = (const float*)d_in[1];  // (T, 512)
  const float* k_pe   = (const float*)d_in[2];  // (T, 64)
  const float* w_kv_b = (const float*)d_in[3];  // (512, 4096)
  const float* w_uv   = (const float*)d_in[4];  // (16, 512, 128)
  float* outp = (float*)d_out;                  // (T, 2048)

  unsigned short* Kb  = (unsigned short*)d_ws;             // (H,T,192) bf16
  unsigned short* Vt  = Kb + (size_t)NHEAD * T_SEQ * DQK;  // (H,128,T) bf16
  unsigned short* Ab  = Vt + (size_t)NHEAD * VDIM * T_SEQ; // (T,512)
  unsigned short* BkT = Ab + (size_t)T_SEQ * LORA_D;       // (2048,512)
  unsigned short* BvT = BkT + (size_t)2048 * LORA_D;       // (2048,512)
  float* Opart = (float*)(BvT + (size_t)2048 * LORA_D);    // 1152 x [64][128] fp32
  float* Lpart = Opart + (size_t)16 * 72 * 64 * 128;       // 1152 x [64] fp32
  const size_t need =
      (size_t)((char*)(Lpart + (size_t)16 * 72 * 64) - (char*)d_ws);
  const int adaptive = (ws_size >= need) ? 1 : 0;   // safe fallback

  stage_all<<<dim3(1024, 3), 256, 0, stream>>>(k_c, w_kv_b, w_uv, Ab, BkT, BvT);
  prep_gemm<<<dim3(16, 32), 256, 0, stream>>>(Ab, BkT, BvT, k_pe, Kb, Vt);
  flash_mfma<<<adaptive ? 1280 : 512, 256, 0, stream>>>(query, Kb, Vt, outp,
                                                        Opart, Lpart, adaptive);
  if (adaptive)
    reduce_out<<<384, 256, 0, stream>>>(Opart, Lpart, outp);
}

// Round 6
// 195.033 us; speedup vs baseline: 1.6069x; 1.3527x over previous
//
#include <hip/hip_runtime.h>
#include <hip/hip_bf16.h>
#include <math.h>

#define T_SEQ 2048
#define NHEAD 16
#define DQK 192      // NOPE + ROPE
#define DNOPE 128
#define DROPE 64
#define LORA_D 512
#define VDIM 128
#define SCALE_F 0.072168783648703216f  // 1/sqrt(192)
#define KC 32
// adaptive split-K: each block handles <= 16 chunks. Per head, tile j
// (q0 = j*64) has n_j = 2j+2 chunks and s_j = ceil(n_j/16) splits:
// j 0..7 -> 1 (direct store), 8..15 -> 2, 16..23 -> 3, 24..31 -> 4.
// blocks/head = 8 + 16 + 24 + 32 = 80; partial slots/head = 72.

typedef short bf16x8 __attribute__((ext_vector_type(8)));   // 8 bf16 = 4 VGPRs
typedef float f32x4 __attribute__((ext_vector_type(4)));

static __device__ __forceinline__ unsigned short f2bf(float x) {
  union { float f; unsigned int u; } v; v.f = x;
  unsigned int r = (v.u + 0x7fff + ((v.u >> 16) & 1)) >> 16;  // RNE
  return (unsigned short)r;
}

// ---------------------------------------------------------------------------
// stage_all: fused input prep. grid (1024, 3).  [proven]
// ---------------------------------------------------------------------------
__global__ __launch_bounds__(256) void stage_all(
    const float* __restrict__ k_c, const float* __restrict__ w_kv_b,
    const float* __restrict__ w_uv, unsigned short* __restrict__ Ab,
    unsigned short* __restrict__ BkT, unsigned short* __restrict__ BvT)
{
  __shared__ float tile[32][33];
  const int bx = blockIdx.x, role = blockIdx.y;
  const int tid = threadIdx.x;
  if (role == 0) {
    int i = (bx * 256 + tid) * 4;
    float4 v = *(const float4*)(k_c + i);
    ushort4 o = {f2bf(v.x), f2bf(v.y), f2bf(v.z), f2bf(v.w)};
    *(ushort4*)(Ab + i) = o;
    return;
  }
  const int tk = tid >> 3, tc4 = (tid & 7) * 4;
  const int wr = tid >> 3, wk4 = (tid & 7) * 4;
  if (role == 1) {
    const int k0 = (bx & 15) * 32, n0 = (bx >> 4) * 32;
    int n = n0 + tc4;
    int col = n + ((n >> 7) << 7);   // skip VDIM half of each head's 256 cols
    float4 v = *(const float4*)&w_kv_b[(size_t)(k0 + tk) * 4096 + col];
    tile[tk][tc4 + 0] = v.x; tile[tk][tc4 + 1] = v.y;
    tile[tk][tc4 + 2] = v.z; tile[tk][tc4 + 3] = v.w;
    __syncthreads();
    ushort4 o = {f2bf(tile[wk4 + 0][wr]), f2bf(tile[wk4 + 1][wr]),
                 f2bf(tile[wk4 + 2][wr]), f2bf(tile[wk4 + 3][wr])};
    *(ushort4*)&BkT[(size_t)(n0 + wr) * LORA_D + k0 + wk4] = o;
  } else {
    const int k0 = (bx & 15) * 32, v0 = ((bx >> 4) & 3) * 32, h = bx >> 6;
    float4 v = *(const float4*)&w_uv[(size_t)h * 65536 + (size_t)(k0 + tk) * 128 + v0 + tc4];
    tile[tk][tc4 + 0] = v.x; tile[tk][tc4 + 1] = v.y;
    tile[tk][tc4 + 2] = v.z; tile[tk][tc4 + 3] = v.w;
    __syncthreads();
    ushort4 o = {f2bf(tile[wk4 + 0][wr]), f2bf(tile[wk4 + 1][wr]),
                 f2bf(tile[wk4 + 2][wr]), f2bf(tile[wk4 + 3][wr])};
    *(ushort4*)&BvT[(size_t)(h * VDIM + v0 + wr) * LORA_D + k0 + wk4] = o;
  }
}

// ---------------------------------------------------------------------------
// prep_gemm: unchanged from R5 (coalesced LDS-staged epilogues).
// ---------------------------------------------------------------------------
__global__ __launch_bounds__(256) void prep_gemm(
    const unsigned short* __restrict__ A, const unsigned short* __restrict__ BkT,
    const unsigned short* __restrict__ BvT, const float* __restrict__ k_pe,
    unsigned short* __restrict__ Kb, unsigned short* __restrict__ Vt)
{
  __shared__ unsigned short SMEM[20480];
  const int m0 = blockIdx.x * 128;
  const int by = blockIdx.y;
  const int isK = (by < 16);
  const int n0 = (isK ? by : (by - 16)) * 128;
  const unsigned short* BT = isK ? BkT : BvT;
  const int tid = threadIdx.x;
  const int wid = tid >> 6, lane = tid & 63;
  const int l16 = lane & 15, quad = lane >> 4;
  const int wm = (wid >> 1) * 64, wn = (wid & 1) * 64;
  const int srow = tid >> 2, sc = tid & 3;
  uint4 areg[2], breg[2];

  auto load_regs = [&](int k0) {
#pragma unroll
    for (int i = 0; i < 2; ++i) {
      int row = srow + i * 64;
      areg[i] = *(const uint4*)(A + (size_t)(m0 + row) * LORA_D + k0 + sc * 8);
      breg[i] = *(const uint4*)(BT + (size_t)(n0 + row) * LORA_D + k0 + sc * 8);
    }
  };
  auto store_lds = [&](int b) {
#pragma unroll
    for (int i = 0; i < 2; ++i) {
      int row = srow + i * 64;
      *(uint4*)((char*)&SMEM[b * 5120 + row * 40] + sc * 16) = areg[i];
      *(uint4*)((char*)&SMEM[10240 + b * 5120 + row * 40] + sc * 16) = breg[i];
    }
  };

  f32x4 acc[4][4];
#pragma unroll
  for (int i = 0; i < 4; ++i)
#pragma unroll
    for (int j = 0; j < 4; ++j) acc[i][j] = (f32x4){0.f, 0.f, 0.f, 0.f};

  load_regs(0);
  store_lds(0);
  __syncthreads();
  for (int kc = 0; kc < 16; ++kc) {
    const int cur = kc & 1;
    if (kc < 15) load_regs((kc + 1) * 32);
    bf16x8 af[4], bfr[4];
#pragma unroll
    for (int t = 0; t < 4; ++t) {
      af[t] = *(const bf16x8*)&SMEM[cur * 5120 + (wm + t * 16 + l16) * 40 + quad * 8];
      bfr[t] = *(const bf16x8*)&SMEM[10240 + cur * 5120 + (wn + t * 16 + l16) * 40 + quad * 8];
    }
#pragma unroll
    for (int mt = 0; mt < 4; ++mt)
#pragma unroll
      for (int nt = 0; nt < 4; ++nt)
        acc[mt][nt] = __builtin_amdgcn_mfma_f32_16x16x32_bf16(af[mt], bfr[nt], acc[mt][nt], 0, 0, 0);
    if (kc < 15) store_lds(cur ^ 1);
    __syncthreads();
  }

  unsigned short* E = SMEM;   // [128][136]
  if (isK) {
#pragma unroll
    for (int mt = 0; mt < 4; ++mt)
#pragma unroll
      for (int nt = 0; nt < 4; ++nt) {
        int ml = wm + mt * 16 + quad * 4;
        int d = wn + nt * 16 + l16;
#pragma unroll
        for (int r = 0; r < 4; ++r)
          E[(ml + r) * 136 + d] = f2bf(acc[mt][nt][r]);
      }
  } else {
#pragma unroll
    for (int mt = 0; mt < 4; ++mt)
#pragma unroll
      for (int nt = 0; nt < 4; ++nt) {
        int ml = wm + mt * 16 + quad * 4;
        int nl = wn + nt * 16 + l16;
#pragma unroll
        for (int r = 0; r < 4; ++r)
          E[nl * 136 + ml + r] = f2bf(acc[mt][nt][r]);
      }
  }
  __syncthreads();

  if (isK) {
    const int h = by;
#pragma unroll
    for (int i = 0; i < 8; ++i) {
      int idx = (i * 256 + tid) * 8;
      int row = idx >> 7, col = idx & 127;
      uint4 v = *(const uint4*)&E[row * 136 + col];
      *(uint4*)&Kb[(size_t)h * (T_SEQ * DQK) + (size_t)(m0 + row) * DQK + col] = v;
    }
    for (int e = tid; e < 128 * 16; e += 256) {
      int row = e >> 4, c4 = (e & 15) * 4;
      float4 v = *(const float4*)&k_pe[(size_t)(m0 + row) * DROPE + c4];
      ushort4 o = {f2bf(v.x), f2bf(v.y), f2bf(v.z), f2bf(v.w)};
      *(ushort4*)&Kb[(size_t)h * (T_SEQ * DQK) + (size_t)(m0 + row) * DQK + DNOPE + c4] = o;
    }
  } else {
#pragma unroll
    for (int i = 0; i < 8; ++i) {
      int idx = (i * 256 + tid) * 8;
      int row = idx >> 7, col = idx & 127;
      uint4 v = *(const uint4*)&E[row * 136 + col];
      *(uint4*)&Vt[(size_t)(n0 + row) * T_SEQ + m0 + col] = v;
    }
  }
}

// ---------------------------------------------------------------------------
// flash_mfma R6: async staging via global_load_lds (T3/T4 minimum-2-phase,
// m97-proven). R5 evidence: VGPR_Count=68 proves the compiler SANK the
// reg-staged prefetch to store_lds -> every chunk ate raw load latency inside
// the barrier (same bug as R4, hidden). global_load_lds has no VGPR footprint
// and cannot be sunk: issued at chunk top, drained by the single syncthreads
// at chunk bottom -> full-compute-phase latency hiding by construction.
// Linear LDS dests (rule: both-sides-or-neither): K [2][32][192] unpadded
// (global chunk is one contiguous 12 KB block), V [2][128][32] unpadded.
// Bank conflicts (measured 6.88M, 8-way on K and V reads) fixed by XOR
// swizzle with the inverse swizzle pre-applied to the global SOURCE address:
// K byte^=(row&7)<<4 -> 2-way (free); V byte^=(row&3)<<4 -> 4-way.
// LDS 46.1 KB -> 3 blocks/CU. Split-K schedule/slots/softmax unchanged.
// ---------------------------------------------------------------------------
__global__ __launch_bounds__(256, 3) void flash_mfma(
    const float* __restrict__ Q, const unsigned short* __restrict__ K,
    const unsigned short* __restrict__ Vt, float* __restrict__ outp,
    float* __restrict__ Opart, float* __restrict__ Lpart, int adaptive)
{
  __shared__ unsigned short SM[2 * KC * DQK];     // K dbuf [2][32][192]; Q stage [64][192]
  __shared__ unsigned short Vsm[2 * VDIM * KC];   // V dbuf [2][128][32]
  __shared__ unsigned short Ps[4][16][40];        // wave-private P tiles
  const int id = blockIdx.x;
  const int h = ((id & 7) << 1) | ((id >> 3) & 1);   // cluster heads per XCD
  int q0, c0, c1, slot, direct;
  if (adaptive) {
    const int b = 79 - (id >> 4);                    // heavy splits first
    int j, sp, s;
    if (b < 8)       { j = b;               sp = 0;            s = 1; }
    else if (b < 24) { j = 8 + (b - 8) / 2; sp = (b - 8) % 2;  s = 2; }
    else if (b < 48) { j = 16 + (b - 24) / 3; sp = (b - 24) % 3; s = 3; }
    else             { j = 24 + (b - 48) / 4; sp = (b - 48) % 4; s = 4; }
    q0 = j * 64;
    const int n = 2 * j + 2;
    c0 = (n * sp) / s;
    c1 = (n * (sp + 1)) / s;
    direct = (s == 1);
    slot = h * 72 + (b - 8);                         // valid iff !direct
  } else {
    q0 = (31 - (id >> 4)) * 64;
    c0 = 0; c1 = q0 / KC + 2; direct = 1; slot = 0;
  }
  const int tid = threadIdx.x;
  const int wid = tid >> 6;
  const int lane = tid & 63;
  const int l16 = lane & 15;
  const int quad = lane >> 4;
  const int myrow = q0 + wid * 16 + quad * 4;
  const int nch = c1 - c0;                           // >= 1 always

  const unsigned short* Kh = K + (size_t)h * T_SEQ * DQK;
  const unsigned short* Vth = Vt + (size_t)h * VDIM * T_SEQ;

  // async global->LDS staging. Dest is linear (base + tid*16); source carries
  // the inverse XOR swizzle so swizzled reads recover the linear layout.
  auto stage = [&](int buf, int s0) {
    const char* Ksrc = (const char*)(Kh + (size_t)s0 * DQK);   // contig 12 KB
    char* Kdst = (char*)&SM[buf * (KC * DQK)];
#pragma unroll
    for (int i = 0; i < 3; ++i) {
      int d = tid * 16 + i * 4096;
      int row = d / 384, c = d - row * 384;
      int cs = c ^ ((row & 7) << 4);
      __builtin_amdgcn_global_load_lds(
          (const unsigned int*)(Ksrc + row * 384 + cs),
          (unsigned int*)(Kdst + d), 16, 0, 0);
    }
    const char* Vsrc = (const char*)Vth + (size_t)s0 * 2;
    char* Vdst = (char*)&Vsm[buf * (VDIM * KC)];
#pragma unroll
    for (int i = 0; i < 2; ++i) {
      int d = tid * 16 + i * 4096;
      int row = d >> 6, c = d & 63;
      int cs = c ^ ((row & 3) << 4);
      __builtin_amdgcn_global_load_lds(
          (const unsigned int*)(Vsrc + (size_t)row * (T_SEQ * 2) + cs),
          (unsigned int*)(Vdst + d), 16, 0, 0);
    }
  };

  // ---- stage Q through the K-dbuf region (exactly 64*192 shorts) ----
  for (int e = tid; e < 64 * 48; e += 256) {
    int row = e / 48, col = (e % 48) * 4;
    float4 q4 = *(const float4*)&Q[(size_t)(q0 + row) * (NHEAD * DQK) + h * DQK + col];
    ushort4 qp = {f2bf(q4.x), f2bf(q4.y), f2bf(q4.z), f2bf(q4.w)};
    *(ushort4*)&SM[row * DQK + col] = qp;
  }
  __syncthreads();
  bf16x8 qf[6];
#pragma unroll
  for (int ks = 0; ks < 6; ++ks)
    qf[ks] = *(const bf16x8*)&SM[(wid * 16 + l16) * DQK + ks * 32 + quad * 8];
  __syncthreads();           // Q reads done before region becomes K buffers
  stage(0, c0 * KC);         // async chunk 0
  __syncthreads();           // drains vmcnt(0): buffer 0 visible

  f32x4 oacc[8];
#pragma unroll
  for (int i = 0; i < 8; ++i) oacc[i] = (f32x4){0.f, 0.f, 0.f, 0.f};
  float lsum[4] = {0.f, 0.f, 0.f, 0.f};

  for (int ck = 0; ck < nch; ++ck) {
    const int cur = ck & 1;
    const int s0 = (c0 + ck) * KC;
    if (ck + 1 < nch) stage(cur ^ 1, s0 + KC);   // async, in flight all chunk

    // ---- S = Q @ K^T (swizzled K reads: 2-way, free) ----
    const char* Kbase = (const char*)&SM[cur * (KC * DQK)];
    f32x4 sacc[2];
    sacc[0] = (f32x4){0.f, 0.f, 0.f, 0.f};
    sacc[1] = (f32x4){0.f, 0.f, 0.f, 0.f};
    __builtin_amdgcn_s_setprio(1);
#pragma unroll
    for (int ks = 0; ks < 6; ++ks) {
      int c = ks * 64 + quad * 16;
      int r0 = l16, r1 = 16 + l16;
      bf16x8 kf0 = *(const bf16x8*)(Kbase + r0 * 384 + (c ^ ((r0 & 7) << 4)));
      bf16x8 kf1 = *(const bf16x8*)(Kbase + r1 * 384 + (c ^ ((r1 & 7) << 4)));
      sacc[0] = __builtin_amdgcn_mfma_f32_16x16x32_bf16(qf[ks], kf0, sacc[0], 0, 0, 0);
      sacc[1] = __builtin_amdgcn_mfma_f32_16x16x32_bf16(qf[ks], kf1, sacc[1], 0, 0, 0);
    }
    __builtin_amdgcn_s_setprio(0);

    // ---- p = exp(s) (no max-subtraction; scores bounded), mask via p=0 ----
#pragma unroll
    for (int r = 0; r < 4; ++r) {
      int row = myrow + r;
      float p0 = (s0 + l16 <= row) ? __expf(sacc[0][r] * SCALE_F) : 0.f;
      float p1 = (s0 + 16 + l16 <= row) ? __expf(sacc[1][r] * SCALE_F) : 0.f;
      lsum[r] += p0 + p1;
      Ps[wid][quad * 4 + r][l16] = f2bf(p0);
      Ps[wid][quad * 4 + r][16 + l16] = f2bf(p1);
    }

    // ---- PV (swizzled V reads: 4-way, was 8-way) ----
    bf16x8 pf = *(const bf16x8*)&Ps[wid][l16][quad * 8];
    const char* Vbase = (const char*)&Vsm[cur * (VDIM * KC)];
    __builtin_amdgcn_s_setprio(1);
#pragma unroll
    for (int nt = 0; nt < 8; ++nt) {
      int vrow = nt * 16 + l16;
      bf16x8 vf = *(const bf16x8*)(Vbase + vrow * 64 + ((quad * 16) ^ ((vrow & 3) << 4)));
      oacc[nt] = __builtin_amdgcn_mfma_f32_16x16x32_bf16(pf, vf, oacc[nt], 0, 0, 0);
    }
    __builtin_amdgcn_s_setprio(0);

    __syncthreads();   // drains vmcnt (next-chunk stage) + lgkm; flip buffers
  }

  // ---- reduce l across the 16 lanes of each quad-row group ----
#pragma unroll
  for (int off = 1; off < 16; off <<= 1)
#pragma unroll
    for (int r = 0; r < 4; ++r) lsum[r] += __shfl_xor(lsum[r], off);

  if (direct) {
    float inv[4];
#pragma unroll
    for (int r = 0; r < 4; ++r) inv[r] = 1.f / lsum[r];
#pragma unroll
    for (int nt = 0; nt < 8; ++nt)
#pragma unroll
      for (int r = 0; r < 4; ++r)
        outp[(size_t)(myrow + r) * (NHEAD * VDIM) + h * VDIM + nt * 16 + l16] =
            oacc[nt][r] * inv[r];
  } else {
    // dense block-local partial slot: [64][128] fp32, fully-written lines
    const int rbase = wid * 16 + quad * 4;
#pragma unroll
    for (int nt = 0; nt < 8; ++nt)
#pragma unroll
      for (int r = 0; r < 4; ++r)
        Opart[(size_t)slot * 8192 + (rbase + r) * 128 + nt * 16 + l16] =
            oacc[nt][r];
    if (l16 == 0)
#pragma unroll
      for (int r = 0; r < 4; ++r)
        Lpart[slot * 64 + rbase + r] = lsum[r];
  }
}

// ---------------------------------------------------------------------------
// reduce_out: combine partial slots for split tiles (j >= 8 only).
// ---------------------------------------------------------------------------
__global__ __launch_bounds__(256) void reduce_out(
    const float* __restrict__ Opart, const float* __restrict__ Lpart,
    float* __restrict__ outp)
{
  const int t = blockIdx.x;
  const int h = t & 15;
  const int j = 8 + (t >> 4);
  int s, b0;
  if (j < 16)      { s = 2; b0 = 8 + (j - 8) * 2; }
  else if (j < 24) { s = 3; b0 = 24 + (j - 16) * 3; }
  else             { s = 4; b0 = 48 + (j - 24) * 4; }
  const int slot = h * 72 + (b0 - 8);
  const int q0 = j * 64;
  const int tid = threadIdx.x;
#pragma unroll
  for (int i = 0; i < 8; ++i) {
    const int f4 = tid + i * 256;            // [0,2048) float4 within tile
    const int row = f4 >> 5, cc = f4 & 31;
    float ax = 0.f, ay = 0.f, az = 0.f, aw = 0.f, l = 0.f;
    for (int k = 0; k < s; ++k) {
      float4 v = ((const float4*)Opart)[(size_t)(slot + k) * 2048 + f4];
      ax += v.x; ay += v.y; az += v.z; aw += v.w;
      l += Lpart[(slot + k) * 64 + row];
    }
    const float inv = 1.f / l;
    float4 o = {ax * inv, ay * inv, az * inv, aw * inv};
    ((float4*)outp)[(size_t)(q0 + row) * 512 + h * 32 + cc] = o;
  }
}

// ---------------------------------------------------------------------------
extern "C" void kernel_launch(void* const* d_in, const int* in_sizes, int n_in,
                              void* d_out, int out_size, void* d_ws, size_t ws_size,
                              hipStream_t stream) {
  const float* query  = (const float*)d_in[0];  // (T, H, 192)
  const float* k_c    = (const float*)d_in[1];  // (T, 512)
  const float* k_pe   = (const float*)d_in[2];  // (T, 64)
  const float* w_kv_b = (const float*)d_in[3];  // (512, 4096)
  const float* w_uv   = (const float*)d_in[4];  // (16, 512, 128)
  float* outp = (float*)d_out;                  // (T, 2048)

  unsigned short* Kb  = (unsigned short*)d_ws;             // (H,T,192) bf16
  unsigned short* Vt  = Kb + (size_t)NHEAD * T_SEQ * DQK;  // (H,128,T) bf16
  unsigned short* Ab  = Vt + (size_t)NHEAD * VDIM * T_SEQ; // (T,512)
  unsigned short* BkT = Ab + (size_t)T_SEQ * LORA_D;       // (2048,512)
  unsigned short* BvT = BkT + (size_t)2048 * LORA_D;       // (2048,512)
  float* Opart = (float*)(BvT + (size_t)2048 * LORA_D);    // 1152 x [64][128] fp32
  float* Lpart = Opart + (size_t)16 * 72 * 64 * 128;       // 1152 x [64] fp32
  const size_t need =
      (size_t)((char*)(Lpart + (size_t)16 * 72 * 64) - (char*)d_ws);
  const int adaptive = (ws_size >= need) ? 1 : 0;   // safe fallback

  stage_all<<<dim3(1024, 3), 256, 0, stream>>>(k_c, w_kv_b, w_uv, Ab, BkT, BvT);
  prep_gemm<<<dim3(16, 32), 256, 0, stream>>>(Ab, BkT, BvT, k_pe, Kb, Vt);
  flash_mfma<<<adaptive ? 1280 : 512, 256, 0, stream>>>(query, Kb, Vt, outp,
                                                        Opart, Lpart, adaptive);
  if (adaptive)
    reduce_out<<<384, 256, 0, stream>>>(Opart, Lpart, outp);
}

// Round 7
// 185.929 us; speedup vs baseline: 1.6855x; 1.0490x over previous
//
#include <hip/hip_runtime.h>
#include <hip/hip_bf16.h>
#include <math.h>

#define T_SEQ 2048
#define NHEAD 16
#define DQK 192      // NOPE + ROPE
#define DNOPE 128
#define DROPE 64
#define LORA_D 512
#define VDIM 128
#define SCALE_F 0.072168783648703216f  // 1/sqrt(192)
#define KC 32
// R7 adaptive split-K over 128-row q-tiles: per head, tile j (q0=j*128) has
// n_j = 4j+4 chunks, s_j = ceil(n_j/16) splits:
// j 0..3 -> 1 (direct), 4..7 -> 2, 8..11 -> 3, 12..15 -> 4.
// blocks/head = 4+8+12+16 = 40; partial slots/head = 36. Grid 640.

typedef short bf16x8 __attribute__((ext_vector_type(8)));   // 8 bf16 = 4 VGPRs
typedef float f32x4 __attribute__((ext_vector_type(4)));

static __device__ __forceinline__ unsigned short f2bf(float x) {
  union { float f; unsigned int u; } v; v.f = x;
  unsigned int r = (v.u + 0x7fff + ((v.u >> 16) & 1)) >> 16;  // RNE
  return (unsigned short)r;
}

// ---------------------------------------------------------------------------
// stage_all: fused input prep. grid (1024, 3).  [proven]
// ---------------------------------------------------------------------------
__global__ __launch_bounds__(256) void stage_all(
    const float* __restrict__ k_c, const float* __restrict__ w_kv_b,
    const float* __restrict__ w_uv, unsigned short* __restrict__ Ab,
    unsigned short* __restrict__ BkT, unsigned short* __restrict__ BvT)
{
  __shared__ float tile[32][33];
  const int bx = blockIdx.x, role = blockIdx.y;
  const int tid = threadIdx.x;
  if (role == 0) {
    int i = (bx * 256 + tid) * 4;
    float4 v = *(const float4*)(k_c + i);
    ushort4 o = {f2bf(v.x), f2bf(v.y), f2bf(v.z), f2bf(v.w)};
    *(ushort4*)(Ab + i) = o;
    return;
  }
  const int tk = tid >> 3, tc4 = (tid & 7) * 4;
  const int wr = tid >> 3, wk4 = (tid & 7) * 4;
  if (role == 1) {
    const int k0 = (bx & 15) * 32, n0 = (bx >> 4) * 32;
    int n = n0 + tc4;
    int col = n + ((n >> 7) << 7);   // skip VDIM half of each head's 256 cols
    float4 v = *(const float4*)&w_kv_b[(size_t)(k0 + tk) * 4096 + col];
    tile[tk][tc4 + 0] = v.x; tile[tk][tc4 + 1] = v.y;
    tile[tk][tc4 + 2] = v.z; tile[tk][tc4 + 3] = v.w;
    __syncthreads();
    ushort4 o = {f2bf(tile[wk4 + 0][wr]), f2bf(tile[wk4 + 1][wr]),
                 f2bf(tile[wk4 + 2][wr]), f2bf(tile[wk4 + 3][wr])};
    *(ushort4*)&BkT[(size_t)(n0 + wr) * LORA_D + k0 + wk4] = o;
  } else {
    const int k0 = (bx & 15) * 32, v0 = ((bx >> 4) & 3) * 32, h = bx >> 6;
    float4 v = *(const float4*)&w_uv[(size_t)h * 65536 + (size_t)(k0 + tk) * 128 + v0 + tc4];
    tile[tk][tc4 + 0] = v.x; tile[tk][tc4 + 1] = v.y;
    tile[tk][tc4 + 2] = v.z; tile[tk][tc4 + 3] = v.w;
    __syncthreads();
    ushort4 o = {f2bf(tile[wk4 + 0][wr]), f2bf(tile[wk4 + 1][wr]),
                 f2bf(tile[wk4 + 2][wr]), f2bf(tile[wk4 + 3][wr])};
    *(ushort4*)&BvT[(size_t)(h * VDIM + v0 + wr) * LORA_D + k0 + wk4] = o;
  }
}

// ---------------------------------------------------------------------------
// prep_gemm R7: async staging via global_load_lds (flash-R6-proven recipe) —
// kills the reg-staging sink (compiler moved loads next to LDS stores, eating
// raw latency per chunk). BK=64, dbuf, 64 KB LDS (grid is 2 blocks/CU anyway,
// per m132 the occupancy cost is zero here). 128B LDS rows + XOR swizzle
// (chunk ^= row&7) -> conflict-free b128 fragment reads. Epilogue unchanged.
// ---------------------------------------------------------------------------
__global__ __launch_bounds__(256) void prep_gemm(
    const unsigned short* __restrict__ A, const unsigned short* __restrict__ BkT,
    const unsigned short* __restrict__ BvT, const float* __restrict__ k_pe,
    unsigned short* __restrict__ Kb, unsigned short* __restrict__ Vt)
{
  // 65536 B: A dbuf [2][128][128B] @0, B dbuf [2][128][128B] @32768 B.
  // Epilogue E[128][136] shorts (34816 B) unions over the dead dbuf region.
  __shared__ unsigned short SMEM[32768];
  const int m0 = blockIdx.x * 128;
  const int by = blockIdx.y;
  const int isK = (by < 16);
  const int n0 = (isK ? by : (by - 16)) * 128;
  const unsigned short* BT = isK ? BkT : BvT;
  const int tid = threadIdx.x;
  const int wid = tid >> 6, lane = tid & 63;
  const int l16 = lane & 15, quad = lane >> 4;
  const int wm = (wid >> 1) * 64, wn = (wid & 1) * 64;

  auto stage_pg = [&](int b, int k0) {
    const char* Asrc = (const char*)(A + (size_t)m0 * LORA_D + k0);
    const char* Bsrc = (const char*)(BT + (size_t)n0 * LORA_D + k0);
    char* Adst = (char*)SMEM + b * 16384;
    char* Bdst = (char*)SMEM + 32768 + b * 16384;
#pragma unroll
    for (int i = 0; i < 4; ++i) {
      int d = tid * 16 + i * 4096;
      int row = d >> 7, c = d & 127;           // c is a multiple of 16
      int sc = c ^ ((row & 7) << 4);           // inverse swizzle on SOURCE
      __builtin_amdgcn_global_load_lds(
          (const unsigned int*)(Asrc + (size_t)row * 1024 + sc),
          (unsigned int*)(Adst + d), 16, 0, 0);
      __builtin_amdgcn_global_load_lds(
          (const unsigned int*)(Bsrc + (size_t)row * 1024 + sc),
          (unsigned int*)(Bdst + d), 16, 0, 0);
    }
  };

  f32x4 acc[4][4];
#pragma unroll
  for (int i = 0; i < 4; ++i)
#pragma unroll
    for (int j = 0; j < 4; ++j) acc[i][j] = (f32x4){0.f, 0.f, 0.f, 0.f};

  stage_pg(0, 0);
  __syncthreads();
  for (int kc = 0; kc < 8; ++kc) {
    const int cur = kc & 1;
    if (kc < 7) stage_pg(cur ^ 1, (kc + 1) * 64);
#pragma unroll
    for (int kk = 0; kk < 2; ++kk) {
      bf16x8 af[4], bfr[4];
#pragma unroll
      for (int t = 0; t < 4; ++t) {
        int ra = wm + t * 16 + l16;
        af[t] = *(const bf16x8*)((char*)SMEM + cur * 16384 + ra * 128 +
                                 (((kk * 4 + quad) ^ (ra & 7)) << 4));
        int rb = wn + t * 16 + l16;
        bfr[t] = *(const bf16x8*)((char*)SMEM + 32768 + cur * 16384 + rb * 128 +
                                  (((kk * 4 + quad) ^ (rb & 7)) << 4));
      }
#pragma unroll
      for (int mt = 0; mt < 4; ++mt)
#pragma unroll
        for (int nt = 0; nt < 4; ++nt)
          acc[mt][nt] = __builtin_amdgcn_mfma_f32_16x16x32_bf16(af[mt], bfr[nt], acc[mt][nt], 0, 0, 0);
    }
    __syncthreads();
  }

  // ---- epilogue: stage bf16 tile in LDS (dbuf dead), store coalesced ----
  unsigned short* E = SMEM;   // [128][136]
  if (isK) {
#pragma unroll
    for (int mt = 0; mt < 4; ++mt)
#pragma unroll
      for (int nt = 0; nt < 4; ++nt) {
        int ml = wm + mt * 16 + quad * 4;
        int d = wn + nt * 16 + l16;
#pragma unroll
        for (int r = 0; r < 4; ++r)
          E[(ml + r) * 136 + d] = f2bf(acc[mt][nt][r]);
      }
  } else {
#pragma unroll
    for (int mt = 0; mt < 4; ++mt)
#pragma unroll
      for (int nt = 0; nt < 4; ++nt) {
        int ml = wm + mt * 16 + quad * 4;
        int nl = wn + nt * 16 + l16;
#pragma unroll
        for (int r = 0; r < 4; ++r)
          E[nl * 136 + ml + r] = f2bf(acc[mt][nt][r]);
      }
  }
  __syncthreads();

  if (isK) {
    const int h = by;
#pragma unroll
    for (int i = 0; i < 8; ++i) {
      int idx = (i * 256 + tid) * 8;
      int row = idx >> 7, col = idx & 127;
      uint4 v = *(const uint4*)&E[row * 136 + col];
      *(uint4*)&Kb[(size_t)h * (T_SEQ * DQK) + (size_t)(m0 + row) * DQK + col] = v;
    }
    for (int e = tid; e < 128 * 16; e += 256) {
      int row = e >> 4, c4 = (e & 15) * 4;
      float4 v = *(const float4*)&k_pe[(size_t)(m0 + row) * DROPE + c4];
      ushort4 o = {f2bf(v.x), f2bf(v.y), f2bf(v.z), f2bf(v.w)};
      *(ushort4*)&Kb[(size_t)h * (T_SEQ * DQK) + (size_t)(m0 + row) * DQK + DNOPE + c4] = o;
    }
  } else {
#pragma unroll
    for (int i = 0; i < 8; ++i) {
      int idx = (i * 256 + tid) * 8;
      int row = idx >> 7, col = idx & 127;
      uint4 v = *(const uint4*)&E[row * 136 + col];
      *(uint4*)&Vt[(size_t)(n0 + row) * T_SEQ + m0 + col] = v;
    }
  }
}

// ---------------------------------------------------------------------------
// flash_mfma R7: 128-row q-tiles (4 waves x 32 rows, two 16-row groups/wave).
// R6 staging/swizzle kept verbatim; MFMA per chunk doubles (40/wave: 24 QK +
// 16 PV) against the same per-chunk fixed costs (5 gload issue, barrier,
// vmcnt drain) -> MFMA:overhead ratio 2x, chunks halve (16896 -> 8704), Q
// traffic halves. VGPR ~165 fits launch_bounds(256,3) (3 blocks/CU via 51.2
// KB LDS). Q staged in two coalesced passes through the K region.
// ---------------------------------------------------------------------------
__global__ __launch_bounds__(256, 3) void flash_mfma(
    const float* __restrict__ Q, const unsigned short* __restrict__ K,
    const unsigned short* __restrict__ Vt, float* __restrict__ outp,
    float* __restrict__ Opart, float* __restrict__ Lpart, int adaptive)
{
  __shared__ unsigned short SM[2 * KC * DQK];     // K dbuf [2][32][192]; Q pass region
  __shared__ unsigned short Vsm[2 * VDIM * KC];   // V dbuf [2][128][32]
  __shared__ unsigned short Ps[4][32][40];        // wave-private P (32 rows)
  const int id = blockIdx.x;
  const int h = ((id & 7) << 1) | ((id >> 3) & 1);   // cluster heads per XCD
  int q0, c0, c1, slot, direct;
  if (adaptive) {
    const int b = 39 - (id >> 4);                    // heavy splits first
    int j, sp, s;
    if (b < 4)       { j = b;                 sp = 0;            s = 1; }
    else if (b < 12) { j = 4 + (b - 4) / 2;   sp = (b - 4) & 1;  s = 2; }
    else if (b < 24) { j = 8 + (b - 12) / 3;  sp = (b - 12) % 3; s = 3; }
    else             { j = 12 + (b - 24) / 4; sp = (b - 24) & 3; s = 4; }
    q0 = j * 128;
    const int n = 4 * j + 4;
    c0 = (n * sp) / s;
    c1 = (n * (sp + 1)) / s;
    direct = (s == 1);
    slot = h * 36 + (b - 4);                         // valid iff !direct
  } else {
    const int j = 15 - (id >> 4);
    q0 = j * 128; c0 = 0; c1 = 4 * j + 4; direct = 1; slot = 0;
  }
  const int tid = threadIdx.x;
  const int wid = tid >> 6;
  const int lane = tid & 63;
  const int l16 = lane & 15;
  const int quad = lane >> 4;
  const int myrow = q0 + wid * 32 + quad * 4;        // + g*16 + r
  const int nch = c1 - c0;                           // >= 1 always

  const unsigned short* Kh = K + (size_t)h * T_SEQ * DQK;
  const unsigned short* Vth = Vt + (size_t)h * VDIM * T_SEQ;

  // async global->LDS staging, linear dest + inverse-swizzled source (R6).
  auto stage = [&](int buf, int s0) {
    const char* Ksrc = (const char*)(Kh + (size_t)s0 * DQK);   // contig 12 KB
    char* Kdst = (char*)&SM[buf * (KC * DQK)];
#pragma unroll
    for (int i = 0; i < 3; ++i) {
      int d = tid * 16 + i * 4096;
      int row = d / 384, c = d - row * 384;
      int cs = c ^ ((row & 7) << 4);
      __builtin_amdgcn_global_load_lds(
          (const unsigned int*)(Ksrc + row * 384 + cs),
          (unsigned int*)(Kdst + d), 16, 0, 0);
    }
    const char* Vsrc = (const char*)Vth + (size_t)s0 * 2;
    char* Vdst = (char*)&Vsm[buf * (VDIM * KC)];
#pragma unroll
    for (int i = 0; i < 2; ++i) {
      int d = tid * 16 + i * 4096;
      int row = d >> 6, c = d & 63;
      int cs = c ^ ((row & 3) << 4);
      __builtin_amdgcn_global_load_lds(
          (const unsigned int*)(Vsrc + (size_t)row * (T_SEQ * 2) + cs),
          (unsigned int*)(Vdst + d), 16, 0, 0);
    }
  };

  // ---- Q fragments: two coalesced passes through the K region ----
  bf16x8 qf[2][6];
#pragma unroll
  for (int p = 0; p < 2; ++p) {
    for (int e = tid; e < 64 * 48; e += 256) {
      int row = e / 48, col = (e % 48) * 4;
      float4 q4 = *(const float4*)&Q[(size_t)(q0 + p * 64 + row) * (NHEAD * DQK) + h * DQK + col];
      ushort4 qp = {f2bf(q4.x), f2bf(q4.y), f2bf(q4.z), f2bf(q4.w)};
      *(ushort4*)&SM[row * DQK + col] = qp;
    }
    __syncthreads();
    if ((wid >> 1) == p) {
      const int lr = (wid & 1) * 32;
#pragma unroll
      for (int g = 0; g < 2; ++g)
#pragma unroll
        for (int ks = 0; ks < 6; ++ks)
          qf[g][ks] = *(const bf16x8*)&SM[(lr + g * 16 + l16) * DQK + ks * 32 + quad * 8];
    }
    __syncthreads();
  }
  stage(0, c0 * KC);         // async chunk 0
  __syncthreads();           // drains vmcnt(0): buffer 0 visible

  f32x4 oacc[2][8];
#pragma unroll
  for (int g = 0; g < 2; ++g)
#pragma unroll
    for (int i = 0; i < 8; ++i) oacc[g][i] = (f32x4){0.f, 0.f, 0.f, 0.f};
  float lsum[2][4] = {{0.f, 0.f, 0.f, 0.f}, {0.f, 0.f, 0.f, 0.f}};

  for (int ck = 0; ck < nch; ++ck) {
    const int cur = ck & 1;
    const int s0 = (c0 + ck) * KC;
    if (ck + 1 < nch) stage(cur ^ 1, s0 + KC);   // async, in flight all chunk

    // ---- S = Q @ K^T: 24 MFMA/wave, K frags shared across both g ----
    const char* Kbase = (const char*)&SM[cur * (KC * DQK)];
    f32x4 sacc[2][2];
    sacc[0][0] = (f32x4){0.f, 0.f, 0.f, 0.f};
    sacc[0][1] = (f32x4){0.f, 0.f, 0.f, 0.f};
    sacc[1][0] = (f32x4){0.f, 0.f, 0.f, 0.f};
    sacc[1][1] = (f32x4){0.f, 0.f, 0.f, 0.f};
    __builtin_amdgcn_s_setprio(1);
#pragma unroll
    for (int ks = 0; ks < 6; ++ks) {
      int c = ks * 64 + quad * 16;
      int r0 = l16, r1 = 16 + l16;
      bf16x8 kf0 = *(const bf16x8*)(Kbase + r0 * 384 + (c ^ ((r0 & 7) << 4)));
      bf16x8 kf1 = *(const bf16x8*)(Kbase + r1 * 384 + (c ^ ((r1 & 7) << 4)));
      sacc[0][0] = __builtin_amdgcn_mfma_f32_16x16x32_bf16(qf[0][ks], kf0, sacc[0][0], 0, 0, 0);
      sacc[0][1] = __builtin_amdgcn_mfma_f32_16x16x32_bf16(qf[0][ks], kf1, sacc[0][1], 0, 0, 0);
      sacc[1][0] = __builtin_amdgcn_mfma_f32_16x16x32_bf16(qf[1][ks], kf0, sacc[1][0], 0, 0, 0);
      sacc[1][1] = __builtin_amdgcn_mfma_f32_16x16x32_bf16(qf[1][ks], kf1, sacc[1][1], 0, 0, 0);
    }
    __builtin_amdgcn_s_setprio(0);

    // ---- p = exp(s) (no max-subtraction; scores bounded), mask via p=0 ----
#pragma unroll
    for (int g = 0; g < 2; ++g)
#pragma unroll
      for (int r = 0; r < 4; ++r) {
        int row = myrow + g * 16 + r;
        float p0 = (s0 + l16 <= row) ? __expf(sacc[g][0][r] * SCALE_F) : 0.f;
        float p1 = (s0 + 16 + l16 <= row) ? __expf(sacc[g][1][r] * SCALE_F) : 0.f;
        lsum[g][r] += p0 + p1;
        Ps[wid][g * 16 + quad * 4 + r][l16] = f2bf(p0);
        Ps[wid][g * 16 + quad * 4 + r][16 + l16] = f2bf(p1);
      }

    // ---- PV: 16 MFMA/wave, V frags shared across both g ----
    bf16x8 pf0 = *(const bf16x8*)&Ps[wid][l16][quad * 8];
    bf16x8 pf1 = *(const bf16x8*)&Ps[wid][16 + l16][quad * 8];
    const char* Vbase = (const char*)&Vsm[cur * (VDIM * KC)];
    __builtin_amdgcn_s_setprio(1);
#pragma unroll
    for (int nt = 0; nt < 8; ++nt) {
      int vrow = nt * 16 + l16;
      bf16x8 vf = *(const bf16x8*)(Vbase + vrow * 64 + ((quad * 16) ^ ((vrow & 3) << 4)));
      oacc[0][nt] = __builtin_amdgcn_mfma_f32_16x16x32_bf16(pf0, vf, oacc[0][nt], 0, 0, 0);
      oacc[1][nt] = __builtin_amdgcn_mfma_f32_16x16x32_bf16(pf1, vf, oacc[1][nt], 0, 0, 0);
    }
    __builtin_amdgcn_s_setprio(0);

    __syncthreads();   // drains vmcnt (next-chunk stage) + lgkm; flip buffers
  }

  // ---- reduce l across the 16 lanes of each quad-row group ----
#pragma unroll
  for (int off = 1; off < 16; off <<= 1)
#pragma unroll
    for (int g = 0; g < 2; ++g)
#pragma unroll
      for (int r = 0; r < 4; ++r) lsum[g][r] += __shfl_xor(lsum[g][r], off);

  if (direct) {
    float inv[2][4];
#pragma unroll
    for (int g = 0; g < 2; ++g)
#pragma unroll
      for (int r = 0; r < 4; ++r) inv[g][r] = 1.f / lsum[g][r];
#pragma unroll
    for (int g = 0; g < 2; ++g)
#pragma unroll
      for (int nt = 0; nt < 8; ++nt)
#pragma unroll
        for (int r = 0; r < 4; ++r)
          outp[(size_t)(myrow + g * 16 + r) * (NHEAD * VDIM) + h * VDIM + nt * 16 + l16] =
              oacc[g][nt][r] * inv[g][r];
  } else {
    // dense block-local partial slot: [128][128] fp32, fully-written lines
    const int rbase = wid * 32 + quad * 4;
#pragma unroll
    for (int g = 0; g < 2; ++g)
#pragma unroll
      for (int nt = 0; nt < 8; ++nt)
#pragma unroll
        for (int r = 0; r < 4; ++r)
          Opart[(size_t)slot * 16384 + (rbase + g * 16 + r) * 128 + nt * 16 + l16] =
              oacc[g][nt][r];
    if (l16 == 0)
#pragma unroll
      for (int g = 0; g < 2; ++g)
#pragma unroll
        for (int r = 0; r < 4; ++r)
          Lpart[slot * 128 + rbase + g * 16 + r] = lsum[g][r];
  }
}

// ---------------------------------------------------------------------------
// reduce_out: combine partial slots for split tiles (j >= 4).
// grid 384 = 16 heads x 12 tiles x 2 half-tiles; sums s in {2,3,4} dense
// 64 KB slots, writes normalized 64x128 output rows.
// ---------------------------------------------------------------------------
__global__ __launch_bounds__(256) void reduce_out(
    const float* __restrict__ Opart, const float* __restrict__ Lpart,
    float* __restrict__ outp)
{
  const int t = blockIdx.x;
  const int h = t & 15;
  const int u = t >> 4;              // [0,24)
  const int j = 4 + (u >> 1);
  const int half = u & 1;
  int s, b0;
  if (j < 8)       { s = 2; b0 = 4 + (j - 4) * 2; }
  else if (j < 12) { s = 3; b0 = 12 + (j - 8) * 3; }
  else             { s = 4; b0 = 24 + (j - 12) * 4; }
  const int slot0 = h * 36 + (b0 - 4);
  const int rowoff = half * 64;
  const int q0 = j * 128 + rowoff;
  const int tid = threadIdx.x;
#pragma unroll
  for (int i = 0; i < 8; ++i) {
    const int f4 = tid + i * 256;            // [0,2048) float4 in half-tile
    const int row = f4 >> 5, cc = f4 & 31;
    float ax = 0.f, ay = 0.f, az = 0.f, aw = 0.f, l = 0.f;
    for (int k = 0; k < s; ++k) {
      float4 v = ((const float4*)Opart)[(size_t)(slot0 + k) * 4096 + (rowoff + row) * 32 + cc];
      ax += v.x; ay += v.y; az += v.z; aw += v.w;
      l += Lpart[(slot0 + k) * 128 + rowoff + row];
    }
    const float inv = 1.f / l;
    float4 o = {ax * inv, ay * inv, az * inv, aw * inv};
    ((float4*)outp)[(size_t)(q0 + row) * 512 + h * 32 + cc] = o;
  }
}

// ---------------------------------------------------------------------------
extern "C" void kernel_launch(void* const* d_in, const int* in_sizes, int n_in,
                              void* d_out, int out_size, void* d_ws, size_t ws_size,
                              hipStream_t stream) {
  const float* query  = (const float*)d_in[0];  // (T, H, 192)
  const float* k_c    = (const float*)d_in[1];  // (T, 512)
  const float* k_pe   = (const float*)d_in[2];  // (T, 64)
  const float* w_kv_b = (const float*)d_in[3];  // (512, 4096)
  const float* w_uv   = (const float*)d_in[4];  // (16, 512, 128)
  float* outp = (float*)d_out;                  // (T, 2048)

  unsigned short* Kb  = (unsigned short*)d_ws;             // (H,T,192) bf16
  unsigned short* Vt  = Kb + (size_t)NHEAD * T_SEQ * DQK;  // (H,128,T) bf16
  unsigned short* Ab  = Vt + (size_t)NHEAD * VDIM * T_SEQ; // (T,512)
  unsigned short* BkT = Ab + (size_t)T_SEQ * LORA_D;       // (2048,512)
  unsigned short* BvT = BkT + (size_t)2048 * LORA_D;       // (2048,512)
  float* Opart = (float*)(BvT + (size_t)2048 * LORA_D);    // 576 x [128][128] fp32
  float* Lpart = Opart + (size_t)576 * 16384;              // 576 x [128] fp32
  const size_t need =
      (size_t)((char*)(Lpart + (size_t)576 * 128) - (char*)d_ws);
  const int adaptive = (ws_size >= need) ? 1 : 0;   // safe fallback

  stage_all<<<dim3(1024, 3), 256, 0, stream>>>(k_c, w_kv_b, w_uv, Ab, BkT, BvT);
  prep_gemm<<<dim3(16, 32), 256, 0, stream>>>(Ab, BkT, BvT, k_pe, Kb, Vt);
  flash_mfma<<<adaptive ? 640 : 256, 256, 0, stream>>>(query, Kb, Vt, outp,
                                                       Opart, Lpart, adaptive);
  if (adaptive)
    reduce_out<<<384, 256, 0, stream>>>(Opart, Lpart, outp);
}

// Round 8
// 170.813 us; speedup vs baseline: 1.8347x; 1.0885x over previous
//
#include <hip/hip_runtime.h>
#include <hip/hip_bf16.h>
#include <math.h>

#define T_SEQ 2048
#define NHEAD 16
#define DQK 192      // NOPE + ROPE
#define DNOPE 128
#define DROPE 64
#define LORA_D 512
#define VDIM 128
#define SCALE_F 0.072168783648703216f  // 1/sqrt(192)
#define KC 32
// adaptive split-K (R6-proven): each block <= 16 chunks. Per head, tile j
// (q0 = j*64) has n_j = 2j+2 chunks, s_j = ceil(n_j/16) splits:
// j 0..7 -> 1 (direct store), 8..15 -> 2, 16..23 -> 3, 24..31 -> 4.
// blocks/head = 80; partial slots/head = 72. Grid 1280.

typedef short bf16x8 __attribute__((ext_vector_type(8)));   // 8 bf16 = 4 VGPRs
typedef float f32x4 __attribute__((ext_vector_type(4)));

static __device__ __forceinline__ unsigned short f2bf(float x) {
  union { float f; unsigned int u; } v; v.f = x;
  unsigned int r = (v.u + 0x7fff + ((v.u >> 16) & 1)) >> 16;  // RNE
  return (unsigned short)r;
}

// ---------------------------------------------------------------------------
// stage_all: fused input prep. grid (1024, 3).  [proven]
// ---------------------------------------------------------------------------
__global__ __launch_bounds__(256) void stage_all(
    const float* __restrict__ k_c, const float* __restrict__ w_kv_b,
    const float* __restrict__ w_uv, unsigned short* __restrict__ Ab,
    unsigned short* __restrict__ BkT, unsigned short* __restrict__ BvT)
{
  __shared__ float tile[32][33];
  const int bx = blockIdx.x, role = blockIdx.y;
  const int tid = threadIdx.x;
  if (role == 0) {
    int i = (bx * 256 + tid) * 4;
    float4 v = *(const float4*)(k_c + i);
    ushort4 o = {f2bf(v.x), f2bf(v.y), f2bf(v.z), f2bf(v.w)};
    *(ushort4*)(Ab + i) = o;
    return;
  }
  const int tk = tid >> 3, tc4 = (tid & 7) * 4;
  const int wr = tid >> 3, wk4 = (tid & 7) * 4;
  if (role == 1) {
    const int k0 = (bx & 15) * 32, n0 = (bx >> 4) * 32;
    int n = n0 + tc4;
    int col = n + ((n >> 7) << 7);   // skip VDIM half of each head's 256 cols
    float4 v = *(const float4*)&w_kv_b[(size_t)(k0 + tk) * 4096 + col];
    tile[tk][tc4 + 0] = v.x; tile[tk][tc4 + 1] = v.y;
    tile[tk][tc4 + 2] = v.z; tile[tk][tc4 + 3] = v.w;
    __syncthreads();
    ushort4 o = {f2bf(tile[wk4 + 0][wr]), f2bf(tile[wk4 + 1][wr]),
                 f2bf(tile[wk4 + 2][wr]), f2bf(tile[wk4 + 3][wr])};
    *(ushort4*)&BkT[(size_t)(n0 + wr) * LORA_D + k0 + wk4] = o;
  } else {
    const int k0 = (bx & 15) * 32, v0 = ((bx >> 4) & 3) * 32, h = bx >> 6;
    float4 v = *(const float4*)&w_uv[(size_t)h * 65536 + (size_t)(k0 + tk) * 128 + v0 + tc4];
    tile[tk][tc4 + 0] = v.x; tile[tk][tc4 + 1] = v.y;
    tile[tk][tc4 + 2] = v.z; tile[tk][tc4 + 3] = v.w;
    __syncthreads();
    ushort4 o = {f2bf(tile[wk4 + 0][wr]), f2bf(tile[wk4 + 1][wr]),
                 f2bf(tile[wk4 + 2][wr]), f2bf(tile[wk4 + 3][wr])};
    *(ushort4*)&BvT[(size_t)(h * VDIM + v0 + wr) * LORA_D + k0 + wk4] = o;
  }
}

// ---------------------------------------------------------------------------
// prep_gemm: R7-proven async version (part of the 195->186 win). BK=64 dbuf
// via global_load_lds (kills the reg-staging sink), XOR-swizzled LDS rows
// (conflict-free b128 fragment reads), coalesced LDS-staged epilogues.
// ---------------------------------------------------------------------------
__global__ __launch_bounds__(256) void prep_gemm(
    const unsigned short* __restrict__ A, const unsigned short* __restrict__ BkT,
    const unsigned short* __restrict__ BvT, const float* __restrict__ k_pe,
    unsigned short* __restrict__ Kb, unsigned short* __restrict__ Vt)
{
  // 65536 B: A dbuf [2][128][128B] @0, B dbuf [2][128][128B] @32768 B.
  // Epilogue E[128][136] shorts (34816 B) unions over the dead dbuf region.
  __shared__ unsigned short SMEM[32768];
  const int m0 = blockIdx.x * 128;
  const int by = blockIdx.y;
  const int isK = (by < 16);
  const int n0 = (isK ? by : (by - 16)) * 128;
  const unsigned short* BT = isK ? BkT : BvT;
  const int tid = threadIdx.x;
  const int wid = tid >> 6, lane = tid & 63;
  const int l16 = lane & 15, quad = lane >> 4;
  const int wm = (wid >> 1) * 64, wn = (wid & 1) * 64;

  auto stage_pg = [&](int b, int k0) {
    const char* Asrc = (const char*)(A + (size_t)m0 * LORA_D + k0);
    const char* Bsrc = (const char*)(BT + (size_t)n0 * LORA_D + k0);
    char* Adst = (char*)SMEM + b * 16384;
    char* Bdst = (char*)SMEM + 32768 + b * 16384;
#pragma unroll
    for (int i = 0; i < 4; ++i) {
      int d = tid * 16 + i * 4096;
      int row = d >> 7, c = d & 127;           // c is a multiple of 16
      int sc = c ^ ((row & 7) << 4);           // inverse swizzle on SOURCE
      __builtin_amdgcn_global_load_lds(
          (const unsigned int*)(Asrc + (size_t)row * 1024 + sc),
          (unsigned int*)(Adst + d), 16, 0, 0);
      __builtin_amdgcn_global_load_lds(
          (const unsigned int*)(Bsrc + (size_t)row * 1024 + sc),
          (unsigned int*)(Bdst + d), 16, 0, 0);
    }
  };

  f32x4 acc[4][4];
#pragma unroll
  for (int i = 0; i < 4; ++i)
#pragma unroll
    for (int j = 0; j < 4; ++j) acc[i][j] = (f32x4){0.f, 0.f, 0.f, 0.f};

  stage_pg(0, 0);
  __syncthreads();
  for (int kc = 0; kc < 8; ++kc) {
    const int cur = kc & 1;
    if (kc < 7) stage_pg(cur ^ 1, (kc + 1) * 64);
#pragma unroll
    for (int kk = 0; kk < 2; ++kk) {
      bf16x8 af[4], bfr[4];
#pragma unroll
      for (int t = 0; t < 4; ++t) {
        int ra = wm + t * 16 + l16;
        af[t] = *(const bf16x8*)((char*)SMEM + cur * 16384 + ra * 128 +
                                 (((kk * 4 + quad) ^ (ra & 7)) << 4));
        int rb = wn + t * 16 + l16;
        bfr[t] = *(const bf16x8*)((char*)SMEM + 32768 + cur * 16384 + rb * 128 +
                                  (((kk * 4 + quad) ^ (rb & 7)) << 4));
      }
#pragma unroll
      for (int mt = 0; mt < 4; ++mt)
#pragma unroll
        for (int nt = 0; nt < 4; ++nt)
          acc[mt][nt] = __builtin_amdgcn_mfma_f32_16x16x32_bf16(af[mt], bfr[nt], acc[mt][nt], 0, 0, 0);
    }
    __syncthreads();
  }

  // ---- epilogue: stage bf16 tile in LDS (dbuf dead), store coalesced ----
  unsigned short* E = SMEM;   // [128][136]
  if (isK) {
#pragma unroll
    for (int mt = 0; mt < 4; ++mt)
#pragma unroll
      for (int nt = 0; nt < 4; ++nt) {
        int ml = wm + mt * 16 + quad * 4;
        int d = wn + nt * 16 + l16;
#pragma unroll
        for (int r = 0; r < 4; ++r)
          E[(ml + r) * 136 + d] = f2bf(acc[mt][nt][r]);
      }
  } else {
#pragma unroll
    for (int mt = 0; mt < 4; ++mt)
#pragma unroll
      for (int nt = 0; nt < 4; ++nt) {
        int ml = wm + mt * 16 + quad * 4;
        int nl = wn + nt * 16 + l16;
#pragma unroll
        for (int r = 0; r < 4; ++r)
          E[nl * 136 + ml + r] = f2bf(acc[mt][nt][r]);
      }
  }
  __syncthreads();

  if (isK) {
    const int h = by;
#pragma unroll
    for (int i = 0; i < 8; ++i) {
      int idx = (i * 256 + tid) * 8;
      int row = idx >> 7, col = idx & 127;
      uint4 v = *(const uint4*)&E[row * 136 + col];
      *(uint4*)&Kb[(size_t)h * (T_SEQ * DQK) + (size_t)(m0 + row) * DQK + col] = v;
    }
    for (int e = tid; e < 128 * 16; e += 256) {
      int row = e >> 4, c4 = (e & 15) * 4;
      float4 v = *(const float4*)&k_pe[(size_t)(m0 + row) * DROPE + c4];
      ushort4 o = {f2bf(v.x), f2bf(v.y), f2bf(v.z), f2bf(v.w)};
      *(ushort4*)&Kb[(size_t)h * (T_SEQ * DQK) + (size_t)(m0 + row) * DQK + DNOPE + c4] = o;
    }
  } else {
#pragma unroll
    for (int i = 0; i < 8; ++i) {
      int idx = (i * 256 + tid) * 8;
      int row = idx >> 7, col = idx & 127;
      uint4 v = *(const uint4*)&E[row * 136 + col];
      *(uint4*)&Vt[(size_t)(n0 + row) * T_SEQ + m0 + col] = v;
    }
  }
}

// ---------------------------------------------------------------------------
// flash_mfma: EXACT R6 version (best measured: 70.3 us, MfmaUtil 12.4%,
// VGPR 68, no spill). 64-row q-tiles, async global_load_lds K/V dbuf with
// both-sides XOR swizzle (K 2-way free, V 4-way), 1 barrier/chunk,
// work-proportional split-K, dense partial slots, no-max softmax, setprio.
// R7's 128-row variant regressed (occupancy 18.7%, scratch traffic) —
// reverted.
// ---------------------------------------------------------------------------
__global__ __launch_bounds__(256, 3) void flash_mfma(
    const float* __restrict__ Q, const unsigned short* __restrict__ K,
    const unsigned short* __restrict__ Vt, float* __restrict__ outp,
    float* __restrict__ Opart, float* __restrict__ Lpart, int adaptive)
{
  __shared__ unsigned short SM[2 * KC * DQK];     // K dbuf [2][32][192]; Q stage [64][192]
  __shared__ unsigned short Vsm[2 * VDIM * KC];   // V dbuf [2][128][32]
  __shared__ unsigned short Ps[4][16][40];        // wave-private P tiles
  const int id = blockIdx.x;
  const int h = ((id & 7) << 1) | ((id >> 3) & 1);   // cluster heads per XCD
  int q0, c0, c1, slot, direct;
  if (adaptive) {
    const int b = 79 - (id >> 4);                    // heavy splits first
    int j, sp, s;
    if (b < 8)       { j = b;               sp = 0;            s = 1; }
    else if (b < 24) { j = 8 + (b - 8) / 2; sp = (b - 8) % 2;  s = 2; }
    else if (b < 48) { j = 16 + (b - 24) / 3; sp = (b - 24) % 3; s = 3; }
    else             { j = 24 + (b - 48) / 4; sp = (b - 48) % 4; s = 4; }
    q0 = j * 64;
    const int n = 2 * j + 2;
    c0 = (n * sp) / s;
    c1 = (n * (sp + 1)) / s;
    direct = (s == 1);
    slot = h * 72 + (b - 8);                         // valid iff !direct
  } else {
    q0 = (31 - (id >> 4)) * 64;
    c0 = 0; c1 = q0 / KC + 2; direct = 1; slot = 0;
  }
  const int tid = threadIdx.x;
  const int wid = tid >> 6;
  const int lane = tid & 63;
  const int l16 = lane & 15;
  const int quad = lane >> 4;
  const int myrow = q0 + wid * 16 + quad * 4;
  const int nch = c1 - c0;                           // >= 1 always

  const unsigned short* Kh = K + (size_t)h * T_SEQ * DQK;
  const unsigned short* Vth = Vt + (size_t)h * VDIM * T_SEQ;

  // async global->LDS staging. Dest is linear (base + tid*16); source carries
  // the inverse XOR swizzle so swizzled reads recover the linear layout.
  auto stage = [&](int buf, int s0) {
    const char* Ksrc = (const char*)(Kh + (size_t)s0 * DQK);   // contig 12 KB
    char* Kdst = (char*)&SM[buf * (KC * DQK)];
#pragma unroll
    for (int i = 0; i < 3; ++i) {
      int d = tid * 16 + i * 4096;
      int row = d / 384, c = d - row * 384;
      int cs = c ^ ((row & 7) << 4);
      __builtin_amdgcn_global_load_lds(
          (const unsigned int*)(Ksrc + row * 384 + cs),
          (unsigned int*)(Kdst + d), 16, 0, 0);
    }
    const char* Vsrc = (const char*)Vth + (size_t)s0 * 2;
    char* Vdst = (char*)&Vsm[buf * (VDIM * KC)];
#pragma unroll
    for (int i = 0; i < 2; ++i) {
      int d = tid * 16 + i * 4096;
      int row = d >> 6, c = d & 63;
      int cs = c ^ ((row & 3) << 4);
      __builtin_amdgcn_global_load_lds(
          (const unsigned int*)(Vsrc + (size_t)row * (T_SEQ * 2) + cs),
          (unsigned int*)(Vdst + d), 16, 0, 0);
    }
  };

  // ---- stage Q through the K-dbuf region (exactly 64*192 shorts) ----
  for (int e = tid; e < 64 * 48; e += 256) {
    int row = e / 48, col = (e % 48) * 4;
    float4 q4 = *(const float4*)&Q[(size_t)(q0 + row) * (NHEAD * DQK) + h * DQK + col];
    ushort4 qp = {f2bf(q4.x), f2bf(q4.y), f2bf(q4.z), f2bf(q4.w)};
    *(ushort4*)&SM[row * DQK + col] = qp;
  }
  __syncthreads();
  bf16x8 qf[6];
#pragma unroll
  for (int ks = 0; ks < 6; ++ks)
    qf[ks] = *(const bf16x8*)&SM[(wid * 16 + l16) * DQK + ks * 32 + quad * 8];
  __syncthreads();           // Q reads done before region becomes K buffers
  stage(0, c0 * KC);         // async chunk 0
  __syncthreads();           // drains vmcnt(0): buffer 0 visible

  f32x4 oacc[8];
#pragma unroll
  for (int i = 0; i < 8; ++i) oacc[i] = (f32x4){0.f, 0.f, 0.f, 0.f};
  float lsum[4] = {0.f, 0.f, 0.f, 0.f};

  for (int ck = 0; ck < nch; ++ck) {
    const int cur = ck & 1;
    const int s0 = (c0 + ck) * KC;
    if (ck + 1 < nch) stage(cur ^ 1, s0 + KC);   // async, in flight all chunk

    // ---- S = Q @ K^T (swizzled K reads: 2-way, free) ----
    const char* Kbase = (const char*)&SM[cur * (KC * DQK)];
    f32x4 sacc[2];
    sacc[0] = (f32x4){0.f, 0.f, 0.f, 0.f};
    sacc[1] = (f32x4){0.f, 0.f, 0.f, 0.f};
    __builtin_amdgcn_s_setprio(1);
#pragma unroll
    for (int ks = 0; ks < 6; ++ks) {
      int c = ks * 64 + quad * 16;
      int r0 = l16, r1 = 16 + l16;
      bf16x8 kf0 = *(const bf16x8*)(Kbase + r0 * 384 + (c ^ ((r0 & 7) << 4)));
      bf16x8 kf1 = *(const bf16x8*)(Kbase + r1 * 384 + (c ^ ((r1 & 7) << 4)));
      sacc[0] = __builtin_amdgcn_mfma_f32_16x16x32_bf16(qf[ks], kf0, sacc[0], 0, 0, 0);
      sacc[1] = __builtin_amdgcn_mfma_f32_16x16x32_bf16(qf[ks], kf1, sacc[1], 0, 0, 0);
    }
    __builtin_amdgcn_s_setprio(0);

    // ---- p = exp(s) (no max-subtraction; scores bounded), mask via p=0 ----
#pragma unroll
    for (int r = 0; r < 4; ++r) {
      int row = myrow + r;
      float p0 = (s0 + l16 <= row) ? __expf(sacc[0][r] * SCALE_F) : 0.f;
      float p1 = (s0 + 16 + l16 <= row) ? __expf(sacc[1][r] * SCALE_F) : 0.f;
      lsum[r] += p0 + p1;
      Ps[wid][quad * 4 + r][l16] = f2bf(p0);
      Ps[wid][quad * 4 + r][16 + l16] = f2bf(p1);
    }

    // ---- PV (swizzled V reads: 4-way, was 8-way) ----
    bf16x8 pf = *(const bf16x8*)&Ps[wid][l16][quad * 8];
    const char* Vbase = (const char*)&Vsm[cur * (VDIM * KC)];
    __builtin_amdgcn_s_setprio(1);
#pragma unroll
    for (int nt = 0; nt < 8; ++nt) {
      int vrow = nt * 16 + l16;
      bf16x8 vf = *(const bf16x8*)(Vbase + vrow * 64 + ((quad * 16) ^ ((vrow & 3) << 4)));
      oacc[nt] = __builtin_amdgcn_mfma_f32_16x16x32_bf16(pf, vf, oacc[nt], 0, 0, 0);
    }
    __builtin_amdgcn_s_setprio(0);

    __syncthreads();   // drains vmcnt (next-chunk stage) + lgkm; flip buffers
  }

  // ---- reduce l across the 16 lanes of each quad-row group ----
#pragma unroll
  for (int off = 1; off < 16; off <<= 1)
#pragma unroll
    for (int r = 0; r < 4; ++r) lsum[r] += __shfl_xor(lsum[r], off);

  if (direct) {
    float inv[4];
#pragma unroll
    for (int r = 0; r < 4; ++r) inv[r] = 1.f / lsum[r];
#pragma unroll
    for (int nt = 0; nt < 8; ++nt)
#pragma unroll
      for (int r = 0; r < 4; ++r)
        outp[(size_t)(myrow + r) * (NHEAD * VDIM) + h * VDIM + nt * 16 + l16] =
            oacc[nt][r] * inv[r];
  } else {
    // dense block-local partial slot: [64][128] fp32, fully-written lines
    const int rbase = wid * 16 + quad * 4;
#pragma unroll
    for (int nt = 0; nt < 8; ++nt)
#pragma unroll
      for (int r = 0; r < 4; ++r)
        Opart[(size_t)slot * 8192 + (rbase + r) * 128 + nt * 16 + l16] =
            oacc[nt][r];
    if (l16 == 0)
#pragma unroll
      for (int r = 0; r < 4; ++r)
        Lpart[slot * 64 + rbase + r] = lsum[r];
  }
}

// ---------------------------------------------------------------------------
// reduce_out: combine partial slots for split tiles (j >= 8 only).
// grid 384 = 16 heads x 24 tiles; sums s in {2,3,4} dense 32 KB slots.
// ---------------------------------------------------------------------------
__global__ __launch_bounds__(256) void reduce_out(
    const float* __restrict__ Opart, const float* __restrict__ Lpart,
    float* __restrict__ outp)
{
  const int t = blockIdx.x;
  const int h = t & 15;
  const int j = 8 + (t >> 4);
  int s, b0;
  if (j < 16)      { s = 2; b0 = 8 + (j - 8) * 2; }
  else if (j < 24) { s = 3; b0 = 24 + (j - 16) * 3; }
  else             { s = 4; b0 = 48 + (j - 24) * 4; }
  const int slot = h * 72 + (b0 - 8);
  const int q0 = j * 64;
  const int tid = threadIdx.x;
#pragma unroll
  for (int i = 0; i < 8; ++i) {
    const int f4 = tid + i * 256;            // [0,2048) float4 within tile
    const int row = f4 >> 5, cc = f4 & 31;
    float ax = 0.f, ay = 0.f, az = 0.f, aw = 0.f, l = 0.f;
    for (int k = 0; k < s; ++k) {
      float4 v = ((const float4*)Opart)[(size_t)(slot + k) * 2048 + f4];
      ax += v.x; ay += v.y; az += v.z; aw += v.w;
      l += Lpart[(slot + k) * 64 + row];
    }
    const float inv = 1.f / l;
    float4 o = {ax * inv, ay * inv, az * inv, aw * inv};
    ((float4*)outp)[(size_t)(q0 + row) * 512 + h * 32 + cc] = o;
  }
}

// ---------------------------------------------------------------------------
extern "C" void kernel_launch(void* const* d_in, const int* in_sizes, int n_in,
                              void* d_out, int out_size, void* d_ws, size_t ws_size,
                              hipStream_t stream) {
  const float* query  = (const float*)d_in[0];  // (T, H, 192)
  const float* k_c    = (const float*)d_in[1];  // (T, 512)
  const float* k_pe   = (const float*)d_in[2];  // (T, 64)
  const float* w_kv_b = (const float*)d_in[3];  // (512, 4096)
  const float* w_uv   = (const float*)d_in[4];  // (16, 512, 128)
  float* outp = (float*)d_out;                  // (T, 2048)

  unsigned short* Kb  = (unsigned short*)d_ws;             // (H,T,192) bf16
  unsigned short* Vt  = Kb + (size_t)NHEAD * T_SEQ * DQK;  // (H,128,T) bf16
  unsigned short* Ab  = Vt + (size_t)NHEAD * VDIM * T_SEQ; // (T,512)
  unsigned short* BkT = Ab + (size_t)T_SEQ * LORA_D;       // (2048,512)
  unsigned short* BvT = BkT + (size_t)2048 * LORA_D;       // (2048,512)
  float* Opart = (float*)(BvT + (size_t)2048 * LORA_D);    // 1152 x [64][128] fp32
  float* Lpart = Opart + (size_t)16 * 72 * 64 * 128;       // 1152 x [64] fp32
  const size_t need =
      (size_t)((char*)(Lpart + (size_t)16 * 72 * 64) - (char*)d_ws);
  const int adaptive = (ws_size >= need) ? 1 : 0;   // safe fallback

  stage_all<<<dim3(1024, 3), 256, 0, stream>>>(k_c, w_kv_b, w_uv, Ab, BkT, BvT);
  prep_gemm<<<dim3(16, 32), 256, 0, stream>>>(Ab, BkT, BvT, k_pe, Kb, Vt);
  flash_mfma<<<adaptive ? 1280 : 512, 256, 0, stream>>>(query, Kb, Vt, outp,
                                                        Opart, Lpart, adaptive);
  if (adaptive)
    reduce_out<<<384, 256, 0, stream>>>(Opart, Lpart, outp);
}

// Round 9
// 168.867 us; speedup vs baseline: 1.8558x; 1.0115x over previous
//
#include <hip/hip_runtime.h>
#include <hip/hip_bf16.h>
#include <math.h>

#define T_SEQ 2048
#define NHEAD 16
#define DQK 192      // NOPE + ROPE
#define DNOPE 128
#define DROPE 64
#define LORA_D 512
#define VDIM 128
#define SCALE_F 0.072168783648703216f  // 1/sqrt(192)
#define KC 32
// adaptive split-K (R6-proven): each block <= 16 chunks. Per head, tile j
// (q0 = j*64) has n_j = 2j+2 chunks, s_j = ceil(n_j/16) splits:
// j 0..7 -> 1 (direct store), 8..15 -> 2, 16..23 -> 3, 24..31 -> 4.
// blocks/head = 80; partial slots/head = 72. Grid 1280.

typedef short bf16x8 __attribute__((ext_vector_type(8)));   // 8 bf16 = 4 VGPRs
typedef float f32x4 __attribute__((ext_vector_type(4)));

static __device__ __forceinline__ unsigned short f2bf(float x) {
  union { float f; unsigned int u; } v; v.f = x;
  unsigned int r = (v.u + 0x7fff + ((v.u >> 16) & 1)) >> 16;  // RNE
  return (unsigned short)r;
}

// ---------------------------------------------------------------------------
// stage_all: fused input prep. grid (1024, 3).  [proven]
// ---------------------------------------------------------------------------
__global__ __launch_bounds__(256) void stage_all(
    const float* __restrict__ k_c, const float* __restrict__ w_kv_b,
    const float* __restrict__ w_uv, unsigned short* __restrict__ Ab,
    unsigned short* __restrict__ BkT, unsigned short* __restrict__ BvT)
{
  __shared__ float tile[32][33];
  const int bx = blockIdx.x, role = blockIdx.y;
  const int tid = threadIdx.x;
  if (role == 0) {
    int i = (bx * 256 + tid) * 4;
    float4 v = *(const float4*)(k_c + i);
    ushort4 o = {f2bf(v.x), f2bf(v.y), f2bf(v.z), f2bf(v.w)};
    *(ushort4*)(Ab + i) = o;
    return;
  }
  const int tk = tid >> 3, tc4 = (tid & 7) * 4;
  const int wr = tid >> 3, wk4 = (tid & 7) * 4;
  if (role == 1) {
    const int k0 = (bx & 15) * 32, n0 = (bx >> 4) * 32;
    int n = n0 + tc4;
    int col = n + ((n >> 7) << 7);   // skip VDIM half of each head's 256 cols
    float4 v = *(const float4*)&w_kv_b[(size_t)(k0 + tk) * 4096 + col];
    tile[tk][tc4 + 0] = v.x; tile[tk][tc4 + 1] = v.y;
    tile[tk][tc4 + 2] = v.z; tile[tk][tc4 + 3] = v.w;
    __syncthreads();
    ushort4 o = {f2bf(tile[wk4 + 0][wr]), f2bf(tile[wk4 + 1][wr]),
                 f2bf(tile[wk4 + 2][wr]), f2bf(tile[wk4 + 3][wr])};
    *(ushort4*)&BkT[(size_t)(n0 + wr) * LORA_D + k0 + wk4] = o;
  } else {
    const int k0 = (bx & 15) * 32, v0 = ((bx >> 4) & 3) * 32, h = bx >> 6;
    float4 v = *(const float4*)&w_uv[(size_t)h * 65536 + (size_t)(k0 + tk) * 128 + v0 + tc4];
    tile[tk][tc4 + 0] = v.x; tile[tk][tc4 + 1] = v.y;
    tile[tk][tc4 + 2] = v.z; tile[tk][tc4 + 3] = v.w;
    __syncthreads();
    ushort4 o = {f2bf(tile[wk4 + 0][wr]), f2bf(tile[wk4 + 1][wr]),
                 f2bf(tile[wk4 + 2][wr]), f2bf(tile[wk4 + 3][wr])};
    *(ushort4*)&BvT[(size_t)(h * VDIM + v0 + wr) * LORA_D + k0 + wk4] = o;
  }
}

// ---------------------------------------------------------------------------
// prep_gemm: R7/R8-proven async version. BK=64 dbuf via global_load_lds,
// XOR-swizzled LDS rows, coalesced LDS-staged epilogues.
// ---------------------------------------------------------------------------
__global__ __launch_bounds__(256) void prep_gemm(
    const unsigned short* __restrict__ A, const unsigned short* __restrict__ BkT,
    const unsigned short* __restrict__ BvT, const float* __restrict__ k_pe,
    unsigned short* __restrict__ Kb, unsigned short* __restrict__ Vt)
{
  __shared__ unsigned short SMEM[32768];
  const int m0 = blockIdx.x * 128;
  const int by = blockIdx.y;
  const int isK = (by < 16);
  const int n0 = (isK ? by : (by - 16)) * 128;
  const unsigned short* BT = isK ? BkT : BvT;
  const int tid = threadIdx.x;
  const int wid = tid >> 6, lane = tid & 63;
  const int l16 = lane & 15, quad = lane >> 4;
  const int wm = (wid >> 1) * 64, wn = (wid & 1) * 64;

  auto stage_pg = [&](int b, int k0) {
    const char* Asrc = (const char*)(A + (size_t)m0 * LORA_D + k0);
    const char* Bsrc = (const char*)(BT + (size_t)n0 * LORA_D + k0);
    char* Adst = (char*)SMEM + b * 16384;
    char* Bdst = (char*)SMEM + 32768 + b * 16384;
#pragma unroll
    for (int i = 0; i < 4; ++i) {
      int d = tid * 16 + i * 4096;
      int row = d >> 7, c = d & 127;
      int sc = c ^ ((row & 7) << 4);
      __builtin_amdgcn_global_load_lds(
          (const unsigned int*)(Asrc + (size_t)row * 1024 + sc),
          (unsigned int*)(Adst + d), 16, 0, 0);
      __builtin_amdgcn_global_load_lds(
          (const unsigned int*)(Bsrc + (size_t)row * 1024 + sc),
          (unsigned int*)(Bdst + d), 16, 0, 0);
    }
  };

  f32x4 acc[4][4];
#pragma unroll
  for (int i = 0; i < 4; ++i)
#pragma unroll
    for (int j = 0; j < 4; ++j) acc[i][j] = (f32x4){0.f, 0.f, 0.f, 0.f};

  stage_pg(0, 0);
  __syncthreads();
  for (int kc = 0; kc < 8; ++kc) {
    const int cur = kc & 1;
    if (kc < 7) stage_pg(cur ^ 1, (kc + 1) * 64);
#pragma unroll
    for (int kk = 0; kk < 2; ++kk) {
      bf16x8 af[4], bfr[4];
#pragma unroll
      for (int t = 0; t < 4; ++t) {
        int ra = wm + t * 16 + l16;
        af[t] = *(const bf16x8*)((char*)SMEM + cur * 16384 + ra * 128 +
                                 (((kk * 4 + quad) ^ (ra & 7)) << 4));
        int rb = wn + t * 16 + l16;
        bfr[t] = *(const bf16x8*)((char*)SMEM + 32768 + cur * 16384 + rb * 128 +
                                  (((kk * 4 + quad) ^ (rb & 7)) << 4));
      }
#pragma unroll
      for (int mt = 0; mt < 4; ++mt)
#pragma unroll
        for (int nt = 0; nt < 4; ++nt)
          acc[mt][nt] = __builtin_amdgcn_mfma_f32_16x16x32_bf16(af[mt], bfr[nt], acc[mt][nt], 0, 0, 0);
    }
    __syncthreads();
  }

  unsigned short* E = SMEM;   // [128][136]
  if (isK) {
#pragma unroll
    for (int mt = 0; mt < 4; ++mt)
#pragma unroll
      for (int nt = 0; nt < 4; ++nt) {
        int ml = wm + mt * 16 + quad * 4;
        int d = wn + nt * 16 + l16;
#pragma unroll
        for (int r = 0; r < 4; ++r)
          E[(ml + r) * 136 + d] = f2bf(acc[mt][nt][r]);
      }
  } else {
#pragma unroll
    for (int mt = 0; mt < 4; ++mt)
#pragma unroll
      for (int nt = 0; nt < 4; ++nt) {
        int ml = wm + mt * 16 + quad * 4;
        int nl = wn + nt * 16 + l16;
#pragma unroll
        for (int r = 0; r < 4; ++r)
          E[nl * 136 + ml + r] = f2bf(acc[mt][nt][r]);
      }
  }
  __syncthreads();

  if (isK) {
    const int h = by;
#pragma unroll
    for (int i = 0; i < 8; ++i) {
      int idx = (i * 256 + tid) * 8;
      int row = idx >> 7, col = idx & 127;
      uint4 v = *(const uint4*)&E[row * 136 + col];
      *(uint4*)&Kb[(size_t)h * (T_SEQ * DQK) + (size_t)(m0 + row) * DQK + col] = v;
    }
    for (int e = tid; e < 128 * 16; e += 256) {
      int row = e >> 4, c4 = (e & 15) * 4;
      float4 v = *(const float4*)&k_pe[(size_t)(m0 + row) * DROPE + c4];
      ushort4 o = {f2bf(v.x), f2bf(v.y), f2bf(v.z), f2bf(v.w)};
      *(ushort4*)&Kb[(size_t)h * (T_SEQ * DQK) + (size_t)(m0 + row) * DQK + DNOPE + c4] = o;
    }
  } else {
#pragma unroll
    for (int i = 0; i < 8; ++i) {
      int idx = (i * 256 + tid) * 8;
      int row = idx >> 7, col = idx & 127;
      uint4 v = *(const uint4*)&E[row * 136 + col];
      *(uint4*)&Vt[(size_t)(n0 + row) * T_SEQ + m0 + col] = v;
    }
  }
}

// ---------------------------------------------------------------------------
// flash_mfma R9: R8 schedule unchanged (async gload_lds dbuf, 1 barrier/chunk,
// split-K). NEW — SIMD-issue diet (R8 analysis: issue-port bound, VALU #1):
// (1) pi-permuted K staging (even global kv rows -> LDS rows 0-15, odd ->
//     16-31). MFMA contraction is order-invariant when P positions and V rows
//     share the permutation; here P' positions land in NATURAL kv order so V
//     is untouched. Lane's kv pair becomes {2*l16, 2*l16+1} = adjacent ->
//     16 manual f2bf + 16 ds_write_b16 collapse to 4 v_cvt_pk_bf16_f32
//     (bit-identical RNE) + 4 ds_write_b32.  (-66 VALU, -12 LDS instr/chunk)
// (2) staging addresses (incl. d/384 and swizzle) precomputed per-thread in
//     the prologue; per chunk only pointer adds remain.  (-30 VALU/chunk)
// ---------------------------------------------------------------------------
__global__ __launch_bounds__(256, 3) void flash_mfma(
    const float* __restrict__ Q, const unsigned short* __restrict__ K,
    const unsigned short* __restrict__ Vt, float* __restrict__ outp,
    float* __restrict__ Opart, float* __restrict__ Lpart, int adaptive)
{
  __shared__ unsigned short SM[2 * KC * DQK];     // K dbuf [2][32][192]; Q stage [64][192]
  __shared__ unsigned short Vsm[2 * VDIM * KC];   // V dbuf [2][128][32]
  __shared__ unsigned short Ps[4][16][40];        // wave-private P' tiles
  const int id = blockIdx.x;
  const int h = ((id & 7) << 1) | ((id >> 3) & 1);   // cluster heads per XCD
  int q0, c0, c1, slot, direct;
  if (adaptive) {
    const int b = 79 - (id >> 4);                    // heavy splits first
    int j, sp, s;
    if (b < 8)       { j = b;               sp = 0;            s = 1; }
    else if (b < 24) { j = 8 + (b - 8) / 2; sp = (b - 8) % 2;  s = 2; }
    else if (b < 48) { j = 16 + (b - 24) / 3; sp = (b - 24) % 3; s = 3; }
    else             { j = 24 + (b - 48) / 4; sp = (b - 48) % 4; s = 4; }
    q0 = j * 64;
    const int n = 2 * j + 2;
    c0 = (n * sp) / s;
    c1 = (n * (sp + 1)) / s;
    direct = (s == 1);
    slot = h * 72 + (b - 8);                         // valid iff !direct
  } else {
    q0 = (31 - (id >> 4)) * 64;
    c0 = 0; c1 = q0 / KC + 2; direct = 1; slot = 0;
  }
  const int tid = threadIdx.x;
  const int wid = tid >> 6;
  const int lane = tid & 63;
  const int l16 = lane & 15;
  const int quad = lane >> 4;
  const int myrow = q0 + wid * 16 + quad * 4;
  const int nch = c1 - c0;                           // >= 1 always

  const unsigned short* Kh = K + (size_t)h * T_SEQ * DQK;
  const unsigned short* Vth = Vt + (size_t)h * VDIM * T_SEQ;

  // ---- precomputed per-thread staging offsets (constant across chunks) ----
  int ksrc_off[3], kdst_off[3];
#pragma unroll
  for (int i = 0; i < 3; ++i) {
    int d = tid * 16 + i * 4096;
    int rho = d / 384, c = d - rho * 384;            // LDS row, col
    int g = ((rho & 15) << 1) | (rho >> 4);          // pi: even rows first
    ksrc_off[i] = g * 384 + (c ^ ((rho & 7) << 4));  // src byte within chunk
    kdst_off[i] = d;
  }
  size_t vsrc_off[2]; int vdst_off[2];
#pragma unroll
  for (int i = 0; i < 2; ++i) {
    int d = tid * 16 + i * 4096;
    int row = d >> 6, c = d & 63;
    vsrc_off[i] = (size_t)row * (T_SEQ * 2) + (c ^ ((row & 3) << 4));
    vdst_off[i] = d;
  }

  auto stage = [&](int buf, int s0) {
    const char* Kc = (const char*)Kh + (size_t)s0 * 384;
    char* Kd = (char*)&SM[buf * (KC * DQK)];
#pragma unroll
    for (int i = 0; i < 3; ++i)
      __builtin_amdgcn_global_load_lds(
          (const unsigned int*)(Kc + ksrc_off[i]),
          (unsigned int*)(Kd + kdst_off[i]), 16, 0, 0);
    const char* Vc = (const char*)Vth + (size_t)s0 * 2;
    char* Vd = (char*)&Vsm[buf * (VDIM * KC)];
#pragma unroll
    for (int i = 0; i < 2; ++i)
      __builtin_amdgcn_global_load_lds(
          (const unsigned int*)(Vc + vsrc_off[i]),
          (unsigned int*)(Vd + vdst_off[i]), 16, 0, 0);
  };

  // ---- stage Q through the K-dbuf region (exactly 64*192 shorts) ----
  for (int e = tid; e < 64 * 48; e += 256) {
    int row = e / 48, col = (e % 48) * 4;
    float4 q4 = *(const float4*)&Q[(size_t)(q0 + row) * (NHEAD * DQK) + h * DQK + col];
    ushort4 qp = {f2bf(q4.x), f2bf(q4.y), f2bf(q4.z), f2bf(q4.w)};
    *(ushort4*)&SM[row * DQK + col] = qp;
  }
  __syncthreads();
  bf16x8 qf[6];
#pragma unroll
  for (int ks = 0; ks < 6; ++ks)
    qf[ks] = *(const bf16x8*)&SM[(wid * 16 + l16) * DQK + ks * 32 + quad * 8];
  __syncthreads();           // Q reads done before region becomes K buffers
  stage(0, c0 * KC);         // async chunk 0
  __syncthreads();           // drains vmcnt(0): buffer 0 visible

  f32x4 oacc[8];
#pragma unroll
  for (int i = 0; i < 8; ++i) oacc[i] = (f32x4){0.f, 0.f, 0.f, 0.f};
  float lsum[4] = {0.f, 0.f, 0.f, 0.f};
  const int kv2 = 2 * l16;   // this lane's (even) kv index within a chunk

  for (int ck = 0; ck < nch; ++ck) {
    const int cur = ck & 1;
    const int s0 = (c0 + ck) * KC;
    if (ck + 1 < nch) stage(cur ^ 1, s0 + KC);   // async, in flight all chunk

    // ---- S = Q @ K^T. LDS rows l16 / 16+l16 hold global kv 2*l16 / 2*l16+1
    //      (pi remap); swizzled K reads unchanged (keyed by LDS row). ----
    const char* Kbase = (const char*)&SM[cur * (KC * DQK)];
    f32x4 sacc[2];
    sacc[0] = (f32x4){0.f, 0.f, 0.f, 0.f};
    sacc[1] = (f32x4){0.f, 0.f, 0.f, 0.f};
    __builtin_amdgcn_s_setprio(1);
#pragma unroll
    for (int ks = 0; ks < 6; ++ks) {
      int c = ks * 64 + quad * 16;
      int r0 = l16, r1 = 16 + l16;
      bf16x8 kf0 = *(const bf16x8*)(Kbase + r0 * 384 + (c ^ ((r0 & 7) << 4)));
      bf16x8 kf1 = *(const bf16x8*)(Kbase + r1 * 384 + (c ^ ((r1 & 7) << 4)));
      sacc[0] = __builtin_amdgcn_mfma_f32_16x16x32_bf16(qf[ks], kf0, sacc[0], 0, 0, 0);
      sacc[1] = __builtin_amdgcn_mfma_f32_16x16x32_bf16(qf[ks], kf1, sacc[1], 0, 0, 0);
    }
    __builtin_amdgcn_s_setprio(0);

    // ---- p = exp(s), mask via p=0; pack pair {kv2, kv2+1} with cvt_pk ----
    const int kvg = s0 + kv2;
#pragma unroll
    for (int r = 0; r < 4; ++r) {
      int row = myrow + r;
      float p0 = (kvg <= row)     ? __expf(sacc[0][r] * SCALE_F) : 0.f;
      float p1 = (kvg + 1 <= row) ? __expf(sacc[1][r] * SCALE_F) : 0.f;
      lsum[r] += p0 + p1;
      unsigned int pk;
      asm("v_cvt_pk_bf16_f32 %0, %1, %2" : "=v"(pk) : "v"(p0), "v"(p1));
      *(unsigned int*)&Ps[wid][quad * 4 + r][kv2] = pk;   // P' natural kv order
    }

    // ---- PV (P' and V both in natural kv order; reads unchanged) ----
    bf16x8 pf = *(const bf16x8*)&Ps[wid][l16][quad * 8];
    const char* Vbase = (const char*)&Vsm[cur * (VDIM * KC)];
    __builtin_amdgcn_s_setprio(1);
#pragma unroll
    for (int nt = 0; nt < 8; ++nt) {
      int vrow = nt * 16 + l16;
      bf16x8 vf = *(const bf16x8*)(Vbase + vrow * 64 + ((quad * 16) ^ ((vrow & 3) << 4)));
      oacc[nt] = __builtin_amdgcn_mfma_f32_16x16x32_bf16(pf, vf, oacc[nt], 0, 0, 0);
    }
    __builtin_amdgcn_s_setprio(0);

    __syncthreads();   // drains vmcnt (next-chunk stage) + lgkm; flip buffers
  }

  // ---- reduce l across the 16 lanes of each quad-row group ----
#pragma unroll
  for (int off = 1; off < 16; off <<= 1)
#pragma unroll
    for (int r = 0; r < 4; ++r) lsum[r] += __shfl_xor(lsum[r], off);

  if (direct) {
    float inv[4];
#pragma unroll
    for (int r = 0; r < 4; ++r) inv[r] = 1.f / lsum[r];
#pragma unroll
    for (int nt = 0; nt < 8; ++nt)
#pragma unroll
      for (int r = 0; r < 4; ++r)
        outp[(size_t)(myrow + r) * (NHEAD * VDIM) + h * VDIM + nt * 16 + l16] =
            oacc[nt][r] * inv[r];
  } else {
    // dense block-local partial slot: [64][128] fp32, fully-written lines
    const int rbase = wid * 16 + quad * 4;
#pragma unroll
    for (int nt = 0; nt < 8; ++nt)
#pragma unroll
      for (int r = 0; r < 4; ++r)
        Opart[(size_t)slot * 8192 + (rbase + r) * 128 + nt * 16 + l16] =
            oacc[nt][r];
    if (l16 == 0)
#pragma unroll
      for (int r = 0; r < 4; ++r)
        Lpart[slot * 64 + rbase + r] = lsum[r];
  }
}

// ---------------------------------------------------------------------------
// reduce_out: combine partial slots for split tiles (j >= 8 only).
// ---------------------------------------------------------------------------
__global__ __launch_bounds__(256) void reduce_out(
    const float* __restrict__ Opart, const float* __restrict__ Lpart,
    float* __restrict__ outp)
{
  const int t = blockIdx.x;
  const int h = t & 15;
  const int j = 8 + (t >> 4);
  int s, b0;
  if (j < 16)      { s = 2; b0 = 8 + (j - 8) * 2; }
  else if (j < 24) { s = 3; b0 = 24 + (j - 16) * 3; }
  else             { s = 4; b0 = 48 + (j - 24) * 4; }
  const int slot = h * 72 + (b0 - 8);
  const int q0 = j * 64;
  const int tid = threadIdx.x;
#pragma unroll
  for (int i = 0; i < 8; ++i) {
    const int f4 = tid + i * 256;            // [0,2048) float4 within tile
    const int row = f4 >> 5, cc = f4 & 31;
    float ax = 0.f, ay = 0.f, az = 0.f, aw = 0.f, l = 0.f;
    for (int k = 0; k < s; ++k) {
      float4 v = ((const float4*)Opart)[(size_t)(slot + k) * 2048 + f4];
      ax += v.x; ay += v.y; az += v.z; aw += v.w;
      l += Lpart[(slot + k) * 64 + row];
    }
    const float inv = 1.f / l;
    float4 o = {ax * inv, ay * inv, az * inv, aw * inv};
    ((float4*)outp)[(size_t)(q0 + row) * 512 + h * 32 + cc] = o;
  }
}

// ---------------------------------------------------------------------------
extern "C" void kernel_launch(void* const* d_in, const int* in_sizes, int n_in,
                              void* d_out, int out_size, void* d_ws, size_t ws_size,
                              hipStream_t stream) {
  const float* query  = (const float*)d_in[0];  // (T, H, 192)
  const float* k_c    = (const float*)d_in[1];  // (T, 512)
  const float* k_pe   = (const float*)d_in[2];  // (T, 64)
  const float* w_kv_b = (const float*)d_in[3];  // (512, 4096)
  const float* w_uv   = (const float*)d_in[4];  // (16, 512, 128)
  float* outp = (float*)d_out;                  // (T, 2048)

  unsigned short* Kb  = (unsigned short*)d_ws;             // (H,T,192) bf16
  unsigned short* Vt  = Kb + (size_t)NHEAD * T_SEQ * DQK;  // (H,128,T) bf16
  unsigned short* Ab  = Vt + (size_t)NHEAD * VDIM * T_SEQ; // (T,512)
  unsigned short* BkT = Ab + (size_t)T_SEQ * LORA_D;       // (2048,512)
  unsigned short* BvT = BkT + (size_t)2048 * LORA_D;       // (2048,512)
  float* Opart = (float*)(BvT + (size_t)2048 * LORA_D);    // 1152 x [64][128] fp32
  float* Lpart = Opart + (size_t)16 * 72 * 64 * 128;       // 1152 x [64] fp32
  const size_t need =
      (size_t)((char*)(Lpart + (size_t)16 * 72 * 64) - (char*)d_ws);
  const int adaptive = (ws_size >= need) ? 1 : 0;   // safe fallback

  stage_all<<<dim3(1024, 3), 256, 0, stream>>>(k_c, w_kv_b, w_uv, Ab, BkT, BvT);
  prep_gemm<<<dim3(16, 32), 256, 0, stream>>>(Ab, BkT, BvT, k_pe, Kb, Vt);
  flash_mfma<<<adaptive ? 1280 : 512, 256, 0, stream>>>(query, Kb, Vt, outp,
                                                        Opart, Lpart, adaptive);
  if (adaptive)
    reduce_out<<<384, 256, 0, stream>>>(Opart, Lpart, outp);
}

// Round 10
// 166.397 us; speedup vs baseline: 1.8834x; 1.0148x over previous
//
#include <hip/hip_runtime.h>
#include <hip/hip_bf16.h>
#include <math.h>

#define T_SEQ 2048
#define NHEAD 16
#define DQK 192      // NOPE + ROPE
#define DNOPE 128
#define DROPE 64
#define LORA_D 512
#define VDIM 128
#define SCALE_F 0.072168783648703216f  // 1/sqrt(192)
#define KC 32
// adaptive split-K (R6-proven): each block <= 16 chunks. Per head, tile j
// (q0 = j*64) has n_j = 2j+2 chunks, s_j = ceil(n_j/16) splits:
// j 0..7 -> 1 (direct store), 8..15 -> 2, 16..23 -> 3, 24..31 -> 4.
// blocks/head = 80; partial slots/head = 72. Grid 1280.

typedef short bf16x8 __attribute__((ext_vector_type(8)));   // 8 bf16 = 4 VGPRs
typedef float f32x4 __attribute__((ext_vector_type(4)));

static __device__ __forceinline__ unsigned short f2bf(float x) {
  union { float f; unsigned int u; } v; v.f = x;
  unsigned int r = (v.u + 0x7fff + ((v.u >> 16) & 1)) >> 16;  // RNE
  return (unsigned short)r;
}

// ---------------------------------------------------------------------------
// stage_all: fused input prep. grid (1024, 3).  [proven]
// ---------------------------------------------------------------------------
__global__ __launch_bounds__(256) void stage_all(
    const float* __restrict__ k_c, const float* __restrict__ w_kv_b,
    const float* __restrict__ w_uv, unsigned short* __restrict__ Ab,
    unsigned short* __restrict__ BkT, unsigned short* __restrict__ BvT)
{
  __shared__ float tile[32][33];
  const int bx = blockIdx.x, role = blockIdx.y;
  const int tid = threadIdx.x;
  if (role == 0) {
    int i = (bx * 256 + tid) * 4;
    float4 v = *(const float4*)(k_c + i);
    ushort4 o = {f2bf(v.x), f2bf(v.y), f2bf(v.z), f2bf(v.w)};
    *(ushort4*)(Ab + i) = o;
    return;
  }
  const int tk = tid >> 3, tc4 = (tid & 7) * 4;
  const int wr = tid >> 3, wk4 = (tid & 7) * 4;
  if (role == 1) {
    const int k0 = (bx & 15) * 32, n0 = (bx >> 4) * 32;
    int n = n0 + tc4;
    int col = n + ((n >> 7) << 7);   // skip VDIM half of each head's 256 cols
    float4 v = *(const float4*)&w_kv_b[(size_t)(k0 + tk) * 4096 + col];
    tile[tk][tc4 + 0] = v.x; tile[tk][tc4 + 1] = v.y;
    tile[tk][tc4 + 2] = v.z; tile[tk][tc4 + 3] = v.w;
    __syncthreads();
    ushort4 o = {f2bf(tile[wk4 + 0][wr]), f2bf(tile[wk4 + 1][wr]),
                 f2bf(tile[wk4 + 2][wr]), f2bf(tile[wk4 + 3][wr])};
    *(ushort4*)&BkT[(size_t)(n0 + wr) * LORA_D + k0 + wk4] = o;
  } else {
    const int k0 = (bx & 15) * 32, v0 = ((bx >> 4) & 3) * 32, h = bx >> 6;
    float4 v = *(const float4*)&w_uv[(size_t)h * 65536 + (size_t)(k0 + tk) * 128 + v0 + tc4];
    tile[tk][tc4 + 0] = v.x; tile[tk][tc4 + 1] = v.y;
    tile[tk][tc4 + 2] = v.z; tile[tk][tc4 + 3] = v.w;
    __syncthreads();
    ushort4 o = {f2bf(tile[wk4 + 0][wr]), f2bf(tile[wk4 + 1][wr]),
                 f2bf(tile[wk4 + 2][wr]), f2bf(tile[wk4 + 3][wr])};
    *(ushort4*)&BvT[(size_t)(h * VDIM + v0 + wr) * LORA_D + k0 + wk4] = o;
  }
}

// ---------------------------------------------------------------------------
// prep_gemm: R7/R8-proven async version. BK=64 dbuf via global_load_lds,
// XOR-swizzled LDS rows, coalesced LDS-staged epilogues.
// ---------------------------------------------------------------------------
__global__ __launch_bounds__(256) void prep_gemm(
    const unsigned short* __restrict__ A, const unsigned short* __restrict__ BkT,
    const unsigned short* __restrict__ BvT, const float* __restrict__ k_pe,
    unsigned short* __restrict__ Kb, unsigned short* __restrict__ Vt)
{
  __shared__ unsigned short SMEM[32768];
  const int m0 = blockIdx.x * 128;
  const int by = blockIdx.y;
  const int isK = (by < 16);
  const int n0 = (isK ? by : (by - 16)) * 128;
  const unsigned short* BT = isK ? BkT : BvT;
  const int tid = threadIdx.x;
  const int wid = tid >> 6, lane = tid & 63;
  const int l16 = lane & 15, quad = lane >> 4;
  const int wm = (wid >> 1) * 64, wn = (wid & 1) * 64;

  auto stage_pg = [&](int b, int k0) {
    const char* Asrc = (const char*)(A + (size_t)m0 * LORA_D + k0);
    const char* Bsrc = (const char*)(BT + (size_t)n0 * LORA_D + k0);
    char* Adst = (char*)SMEM + b * 16384;
    char* Bdst = (char*)SMEM + 32768 + b * 16384;
#pragma unroll
    for (int i = 0; i < 4; ++i) {
      int d = tid * 16 + i * 4096;
      int row = d >> 7, c = d & 127;
      int sc = c ^ ((row & 7) << 4);
      __builtin_amdgcn_global_load_lds(
          (const unsigned int*)(Asrc + (size_t)row * 1024 + sc),
          (unsigned int*)(Adst + d), 16, 0, 0);
      __builtin_amdgcn_global_load_lds(
          (const unsigned int*)(Bsrc + (size_t)row * 1024 + sc),
          (unsigned int*)(Bdst + d), 16, 0, 0);
    }
  };

  f32x4 acc[4][4];
#pragma unroll
  for (int i = 0; i < 4; ++i)
#pragma unroll
    for (int j = 0; j < 4; ++j) acc[i][j] = (f32x4){0.f, 0.f, 0.f, 0.f};

  stage_pg(0, 0);
  __syncthreads();
  for (int kc = 0; kc < 8; ++kc) {
    const int cur = kc & 1;
    if (kc < 7) stage_pg(cur ^ 1, (kc + 1) * 64);
#pragma unroll
    for (int kk = 0; kk < 2; ++kk) {
      bf16x8 af[4], bfr[4];
#pragma unroll
      for (int t = 0; t < 4; ++t) {
        int ra = wm + t * 16 + l16;
        af[t] = *(const bf16x8*)((char*)SMEM + cur * 16384 + ra * 128 +
                                 (((kk * 4 + quad) ^ (ra & 7)) << 4));
        int rb = wn + t * 16 + l16;
        bfr[t] = *(const bf16x8*)((char*)SMEM + 32768 + cur * 16384 + rb * 128 +
                                  (((kk * 4 + quad) ^ (rb & 7)) << 4));
      }
#pragma unroll
      for (int mt = 0; mt < 4; ++mt)
#pragma unroll
        for (int nt = 0; nt < 4; ++nt)
          acc[mt][nt] = __builtin_amdgcn_mfma_f32_16x16x32_bf16(af[mt], bfr[nt], acc[mt][nt], 0, 0, 0);
    }
    __syncthreads();
  }

  unsigned short* E = SMEM;   // [128][136]
  if (isK) {
#pragma unroll
    for (int mt = 0; mt < 4; ++mt)
#pragma unroll
      for (int nt = 0; nt < 4; ++nt) {
        int ml = wm + mt * 16 + quad * 4;
        int d = wn + nt * 16 + l16;
#pragma unroll
        for (int r = 0; r < 4; ++r)
          E[(ml + r) * 136 + d] = f2bf(acc[mt][nt][r]);
      }
  } else {
#pragma unroll
    for (int mt = 0; mt < 4; ++mt)
#pragma unroll
      for (int nt = 0; nt < 4; ++nt) {
        int ml = wm + mt * 16 + quad * 4;
        int nl = wn + nt * 16 + l16;
#pragma unroll
        for (int r = 0; r < 4; ++r)
          E[nl * 136 + ml + r] = f2bf(acc[mt][nt][r]);
      }
  }
  __syncthreads();

  if (isK) {
    const int h = by;
#pragma unroll
    for (int i = 0; i < 8; ++i) {
      int idx = (i * 256 + tid) * 8;
      int row = idx >> 7, col = idx & 127;
      uint4 v = *(const uint4*)&E[row * 136 + col];
      *(uint4*)&Kb[(size_t)h * (T_SEQ * DQK) + (size_t)(m0 + row) * DQK + col] = v;
    }
    for (int e = tid; e < 128 * 16; e += 256) {
      int row = e >> 4, c4 = (e & 15) * 4;
      float4 v = *(const float4*)&k_pe[(size_t)(m0 + row) * DROPE + c4];
      ushort4 o = {f2bf(v.x), f2bf(v.y), f2bf(v.z), f2bf(v.w)};
      *(ushort4*)&Kb[(size_t)h * (T_SEQ * DQK) + (size_t)(m0 + row) * DQK + DNOPE + c4] = o;
    }
  } else {
#pragma unroll
    for (int i = 0; i < 8; ++i) {
      int idx = (i * 256 + tid) * 8;
      int row = idx >> 7, col = idx & 127;
      uint4 v = *(const uint4*)&E[row * 136 + col];
      *(uint4*)&Vt[(size_t)(n0 + row) * T_SEQ + m0 + col] = v;
    }
  }
}

// ---------------------------------------------------------------------------
// flash_mfma R10: Ps ELIMINATED via swapped QK^T (T12). sacc = mfma(K, Q)
// gives S^T with q lane-local (q = l16) and kv on quad/reg axis -> P packs
// in-register via v_cvt_pk_bf16_f32 (bit-identical RNE) and an 8-shfl
// cross-quad exchange builds the PV A-fragment directly:
//   srcA = l16 + ((quad&1)<<5), srcB = srcA+16; lower quads take sacc0
//   words, upper take sacc1 words (derivation verified against the
//   A-fragment map: lane gets kv = quad*8..quad*8+7 for its q = l16 row).
// PV D-layout is unchanged -> epilogue/split-K identical to R8/R9.
// LDS 46080 -> 40960 B (K dbuf 24K + V dbuf 16K) = EXACTLY 4 blocks/CU
// (was 3): occupancy cap 37.5% -> 50%, 4-way wave overlap hides the chunk
// chain. launch_bounds(256,4) caps VGPR at 128 (est ~95).
// ---------------------------------------------------------------------------
__global__ __launch_bounds__(256, 4) void flash_mfma(
    const float* __restrict__ Q, const unsigned short* __restrict__ K,
    const unsigned short* __restrict__ Vt, float* __restrict__ outp,
    float* __restrict__ Opart, float* __restrict__ Lpart, int adaptive)
{
  __shared__ unsigned short SM[2 * KC * DQK];     // K dbuf [2][32][192]; Q stage [64][192]
  __shared__ unsigned short Vsm[2 * VDIM * KC];   // V dbuf [2][128][32]
  const int id = blockIdx.x;
  const int h = ((id & 7) << 1) | ((id >> 3) & 1);   // cluster heads per XCD
  int q0, c0, c1, slot, direct;
  if (adaptive) {
    const int b = 79 - (id >> 4);                    // heavy splits first
    int j, sp, s;
    if (b < 8)       { j = b;               sp = 0;            s = 1; }
    else if (b < 24) { j = 8 + (b - 8) / 2; sp = (b - 8) % 2;  s = 2; }
    else if (b < 48) { j = 16 + (b - 24) / 3; sp = (b - 24) % 3; s = 3; }
    else             { j = 24 + (b - 48) / 4; sp = (b - 48) % 4; s = 4; }
    q0 = j * 64;
    const int n = 2 * j + 2;
    c0 = (n * sp) / s;
    c1 = (n * (sp + 1)) / s;
    direct = (s == 1);
    slot = h * 72 + (b - 8);                         // valid iff !direct
  } else {
    q0 = (31 - (id >> 4)) * 64;
    c0 = 0; c1 = q0 / KC + 2; direct = 1; slot = 0;
  }
  const int tid = threadIdx.x;
  const int wid = tid >> 6;
  const int lane = tid & 63;
  const int l16 = lane & 15;
  const int quad = lane >> 4;
  const int myrow = q0 + wid * 16 + quad * 4;        // output-row base (D rows)
  const int qrow  = q0 + wid * 16 + l16;             // this lane's q in S^T
  const int nch = c1 - c0;                           // >= 1 always

  const unsigned short* Kh = K + (size_t)h * T_SEQ * DQK;
  const unsigned short* Vth = Vt + (size_t)h * VDIM * T_SEQ;

  // ---- precomputed per-thread staging offsets (linear K; R9's pi dropped) --
  int ksrc_off[3], kdst_off[3];
#pragma unroll
  for (int i = 0; i < 3; ++i) {
    int d = tid * 16 + i * 4096;
    int rho = d / 384, c = d - rho * 384;
    ksrc_off[i] = rho * 384 + (c ^ ((rho & 7) << 4));
    kdst_off[i] = d;
  }
  size_t vsrc_off[2]; int vdst_off[2];
#pragma unroll
  for (int i = 0; i < 2; ++i) {
    int d = tid * 16 + i * 4096;
    int row = d >> 6, c = d & 63;
    vsrc_off[i] = (size_t)row * (T_SEQ * 2) + (c ^ ((row & 3) << 4));
    vdst_off[i] = d;
  }

  auto stage = [&](int buf, int s0) {
    const char* Kc = (const char*)Kh + (size_t)s0 * 384;
    char* Kd = (char*)&SM[buf * (KC * DQK)];
#pragma unroll
    for (int i = 0; i < 3; ++i)
      __builtin_amdgcn_global_load_lds(
          (const unsigned int*)(Kc + ksrc_off[i]),
          (unsigned int*)(Kd + kdst_off[i]), 16, 0, 0);
    const char* Vc = (const char*)Vth + (size_t)s0 * 2;
    char* Vd = (char*)&Vsm[buf * (VDIM * KC)];
#pragma unroll
    for (int i = 0; i < 2; ++i)
      __builtin_amdgcn_global_load_lds(
          (const unsigned int*)(Vc + vsrc_off[i]),
          (unsigned int*)(Vd + vdst_off[i]), 16, 0, 0);
  };

  // ---- stage Q through the K-dbuf region (exactly 64*192 shorts) ----
  for (int e = tid; e < 64 * 48; e += 256) {
    int row = e / 48, col = (e % 48) * 4;
    float4 q4 = *(const float4*)&Q[(size_t)(q0 + row) * (NHEAD * DQK) + h * DQK + col];
    ushort4 qp = {f2bf(q4.x), f2bf(q4.y), f2bf(q4.z), f2bf(q4.w)};
    *(ushort4*)&SM[row * DQK + col] = qp;
  }
  __syncthreads();
  bf16x8 qf[6];
#pragma unroll
  for (int ks = 0; ks < 6; ++ks)
    qf[ks] = *(const bf16x8*)&SM[(wid * 16 + l16) * DQK + ks * 32 + quad * 8];
  __syncthreads();           // Q reads done before region becomes K buffers
  stage(0, c0 * KC);         // async chunk 0
  __syncthreads();           // drains vmcnt(0): buffer 0 visible

  f32x4 oacc[8];
#pragma unroll
  for (int i = 0; i < 8; ++i) oacc[i] = (f32x4){0.f, 0.f, 0.f, 0.f};
  float lsum = 0.f;          // per-lane: all kv for q = qrow (kv on quad axis)

  for (int ck = 0; ck < nch; ++ck) {
    const int cur = ck & 1;
    const int s0 = (c0 + ck) * KC;
    if (ck + 1 < nch) stage(cur ^ 1, s0 + KC);   // async, in flight all chunk

    // ---- S^T = K @ Q^T (swapped operands; fragment layouts symmetric) ----
    const char* Kbase = (const char*)&SM[cur * (KC * DQK)];
    f32x4 sacc0 = (f32x4){0.f, 0.f, 0.f, 0.f};
    f32x4 sacc1 = (f32x4){0.f, 0.f, 0.f, 0.f};
    __builtin_amdgcn_s_setprio(1);
#pragma unroll
    for (int ks = 0; ks < 6; ++ks) {
      int c = ks * 64 + quad * 16;
      int r0 = l16, r1 = 16 + l16;
      bf16x8 kf0 = *(const bf16x8*)(Kbase + r0 * 384 + (c ^ ((r0 & 7) << 4)));
      bf16x8 kf1 = *(const bf16x8*)(Kbase + r1 * 384 + (c ^ ((r1 & 7) << 4)));
      sacc0 = __builtin_amdgcn_mfma_f32_16x16x32_bf16(kf0, qf[ks], sacc0, 0, 0, 0);
      sacc1 = __builtin_amdgcn_mfma_f32_16x16x32_bf16(kf1, qf[ks], sacc1, 0, 0, 0);
    }
    __builtin_amdgcn_s_setprio(0);

    // ---- p = exp(s), mask via p=0. Lane: q=qrow, kv = s0 + {quad*4+r,
    //      16+quad*4+r}. Pack adjacent pairs in-register. ----
    float p0[4], p1[4];
#pragma unroll
    for (int r = 0; r < 4; ++r) {
      int kva = s0 + quad * 4 + r;
      p0[r] = (kva <= qrow)      ? __expf(sacc0[r] * SCALE_F) : 0.f;
      p1[r] = (kva + 16 <= qrow) ? __expf(sacc1[r] * SCALE_F) : 0.f;
      lsum += p0[r] + p1[r];
    }
    unsigned int A0, A1, B0, B1;
    asm("v_cvt_pk_bf16_f32 %0, %1, %2" : "=v"(A0) : "v"(p0[0]), "v"(p0[1]));
    asm("v_cvt_pk_bf16_f32 %0, %1, %2" : "=v"(A1) : "v"(p0[2]), "v"(p0[3]));
    asm("v_cvt_pk_bf16_f32 %0, %1, %2" : "=v"(B0) : "v"(p1[0]), "v"(p1[1]));
    asm("v_cvt_pk_bf16_f32 %0, %1, %2" : "=v"(B1) : "v"(p1[2]), "v"(p1[3]));

    // ---- cross-quad exchange -> PV A-fragment (kv = quad*8..quad*8+7) ----
    const int srcA = l16 + ((quad & 1) << 5);
    const int srcB = srcA + 16;
    int xa0 = __shfl((int)A0, srcA, 64), ya0 = __shfl((int)B0, srcA, 64);
    int xa1 = __shfl((int)A1, srcA, 64), ya1 = __shfl((int)B1, srcA, 64);
    int xb0 = __shfl((int)A0, srcB, 64), yb0 = __shfl((int)B0, srcB, 64);
    int xb1 = __shfl((int)A1, srcB, 64), yb1 = __shfl((int)B1, srcB, 64);
    const bool lower = (quad < 2);
    union { unsigned int u[4]; bf16x8 v; } pw;
    pw.u[0] = lower ? (unsigned)xa0 : (unsigned)ya0;
    pw.u[1] = lower ? (unsigned)xa1 : (unsigned)ya1;
    pw.u[2] = lower ? (unsigned)xb0 : (unsigned)yb0;
    pw.u[3] = lower ? (unsigned)xb1 : (unsigned)yb1;
    bf16x8 pf = pw.v;

    // ---- PV (D rows = quad*4+r -> same output layout as before) ----
    const char* Vbase = (const char*)&Vsm[cur * (VDIM * KC)];
    __builtin_amdgcn_s_setprio(1);
#pragma unroll
    for (int nt = 0; nt < 8; ++nt) {
      int vrow = nt * 16 + l16;
      bf16x8 vf = *(const bf16x8*)(Vbase + vrow * 64 + ((quad * 16) ^ ((vrow & 3) << 4)));
      oacc[nt] = __builtin_amdgcn_mfma_f32_16x16x32_bf16(pf, vf, oacc[nt], 0, 0, 0);
    }
    __builtin_amdgcn_s_setprio(0);

    __syncthreads();   // drains vmcnt (next-chunk stage) + lgkm; flip buffers
  }

  // ---- reduce lsum across quads (kv axis); all quads then hold q=l16 total --
  lsum += __shfl_xor(lsum, 16);
  lsum += __shfl_xor(lsum, 32);
  // redistribute to output-row layout: row r of this lane is q = quad*4+r
  float rowsum[4];
#pragma unroll
  for (int r = 0; r < 4; ++r) rowsum[r] = __shfl(lsum, quad * 4 + r, 64);

  if (direct) {
    float inv[4];
#pragma unroll
    for (int r = 0; r < 4; ++r) inv[r] = 1.f / rowsum[r];
#pragma unroll
    for (int nt = 0; nt < 8; ++nt)
#pragma unroll
      for (int r = 0; r < 4; ++r)
        outp[(size_t)(myrow + r) * (NHEAD * VDIM) + h * VDIM + nt * 16 + l16] =
            oacc[nt][r] * inv[r];
  } else {
    // dense block-local partial slot: [64][128] fp32, fully-written lines
    const int rbase = wid * 16 + quad * 4;
#pragma unroll
    for (int nt = 0; nt < 8; ++nt)
#pragma unroll
      for (int r = 0; r < 4; ++r)
        Opart[(size_t)slot * 8192 + (rbase + r) * 128 + nt * 16 + l16] =
            oacc[nt][r];
    if (l16 == 0)
#pragma unroll
      for (int r = 0; r < 4; ++r)
        Lpart[slot * 64 + rbase + r] = rowsum[r];
  }
}

// ---------------------------------------------------------------------------
// reduce_out: combine partial slots for split tiles (j >= 8 only).
// ---------------------------------------------------------------------------
__global__ __launch_bounds__(256) void reduce_out(
    const float* __restrict__ Opart, const float* __restrict__ Lpart,
    float* __restrict__ outp)
{
  const int t = blockIdx.x;
  const int h = t & 15;
  const int j = 8 + (t >> 4);
  int s, b0;
  if (j < 16)      { s = 2; b0 = 8 + (j - 8) * 2; }
  else if (j < 24) { s = 3; b0 = 24 + (j - 16) * 3; }
  else             { s = 4; b0 = 48 + (j - 24) * 4; }
  const int slot = h * 72 + (b0 - 8);
  const int q0 = j * 64;
  const int tid = threadIdx.x;
#pragma unroll
  for (int i = 0; i < 8; ++i) {
    const int f4 = tid + i * 256;            // [0,2048) float4 within tile
    const int row = f4 >> 5, cc = f4 & 31;
    float ax = 0.f, ay = 0.f, az = 0.f, aw = 0.f, l = 0.f;
    for (int k = 0; k < s; ++k) {
      float4 v = ((const float4*)Opart)[(size_t)(slot + k) * 2048 + f4];
      ax += v.x; ay += v.y; az += v.z; aw += v.w;
      l += Lpart[(slot + k) * 64 + row];
    }
    const float inv = 1.f / l;
    float4 o = {ax * inv, ay * inv, az * inv, aw * inv};
    ((float4*)outp)[(size_t)(q0 + row) * 512 + h * 32 + cc] = o;
  }
}

// ---------------------------------------------------------------------------
extern "C" void kernel_launch(void* const* d_in, const int* in_sizes, int n_in,
                              void* d_out, int out_size, void* d_ws, size_t ws_size,
                              hipStream_t stream) {
  const float* query  = (const float*)d_in[0];  // (T, H, 192)
  const float* k_c    = (const float*)d_in[1];  // (T, 512)
  const float* k_pe   = (const float*)d_in[2];  // (T, 64)
  const float* w_kv_b = (const float*)d_in[3];  // (512, 4096)
  const float* w_uv   = (const float*)d_in[4];  // (16, 512, 128)
  float* outp = (float*)d_out;                  // (T, 2048)

  unsigned short* Kb  = (unsigned short*)d_ws;             // (H,T,192) bf16
  unsigned short* Vt  = Kb + (size_t)NHEAD * T_SEQ * DQK;  // (H,128,T) bf16
  unsigned short* Ab  = Vt + (size_t)NHEAD * VDIM * T_SEQ; // (T,512)
  unsigned short* BkT = Ab + (size_t)T_SEQ * LORA_D;       // (2048,512)
  unsigned short* BvT = BkT + (size_t)2048 * LORA_D;       // (2048,512)
  float* Opart = (float*)(BvT + (size_t)2048 * LORA_D);    // 1152 x [64][128] fp32
  float* Lpart = Opart + (size_t)16 * 72 * 64 * 128;       // 1152 x [64] fp32
  const size_t need =
      (size_t)((char*)(Lpart + (size_t)16 * 72 * 64) - (char*)d_ws);
  const int adaptive = (ws_size >= need) ? 1 : 0;   // safe fallback

  stage_all<<<dim3(1024, 3), 256, 0, stream>>>(k_c, w_kv_b, w_uv, Ab, BkT, BvT);
  prep_gemm<<<dim3(16, 32), 256, 0, stream>>>(Ab, BkT, BvT, k_pe, Kb, Vt);
  flash_mfma<<<adaptive ? 1280 : 512, 256, 0, stream>>>(query, Kb, Vt, outp,
                                                        Opart, Lpart, adaptive);
  if (adaptive)
    reduce_out<<<384, 256, 0, stream>>>(Opart, Lpart, outp);
}